// Round 1
// baseline (542.994 us; speedup 1.0000x reference)
//
#include <hip/hip_runtime.h>
#include <math.h>

#define N_EDGES_C 1048576
#define N_TOTAL_C 65536

__device__ __forceinline__ float sigf(float x){ return 1.0f/(1.0f+expf(-x)); }
__device__ __forceinline__ float lrelu(float x){ return (x>=0.f)? x : 0.2f*x; }

// ---------------- 1. node transform: xp = x @ W_gat, asrc/adst ----------------
__global__ void node_transform(const float* __restrict__ x, const float* __restrict__ Wg,
                               const float* __restrict__ a_src, const float* __restrict__ a_dst,
                               float* __restrict__ xp, float* __restrict__ asrc, float* __restrict__ adst)
{
    __shared__ float Ws[12*96];
    __shared__ float as_s[96], ad_s[96];
    int tid = threadIdx.x;
    for (int i = tid; i < 1152; i += 256) Ws[i] = Wg[i];
    if (tid < 96) { as_s[tid] = a_src[tid]; ad_s[tid] = a_dst[tid]; }
    __syncthreads();
    int n = blockIdx.x * 256 + tid;
    const float4* xv = (const float4*)(x + (size_t)n * 12);
    float4 v0 = xv[0], v1 = xv[1], v2 = xv[2];
    float xr[12] = {v0.x,v0.y,v0.z,v0.w, v1.x,v1.y,v1.z,v1.w, v2.x,v2.y,v2.z,v2.w};
    float* xpr = xp + (size_t)n * 96;
    #pragma unroll
    for (int h = 0; h < 8; h++) {
        float xph[12];
        #pragma unroll
        for (int c = 0; c < 12; c++) {
            float acc = 0.f;
            #pragma unroll
            for (int k = 0; k < 12; k++) acc += xr[k] * Ws[k*96 + h*12 + c];
            xph[c] = acc;
        }
        float4* o = (float4*)(xpr + h*12);
        o[0] = make_float4(xph[0],xph[1],xph[2],xph[3]);
        o[1] = make_float4(xph[4],xph[5],xph[6],xph[7]);
        o[2] = make_float4(xph[8],xph[9],xph[10],xph[11]);
        float sa = 0.f, sd = 0.f;
        #pragma unroll
        for (int c = 0; c < 12; c++) { sa += xph[c]*as_s[h*12+c]; sd += xph[c]*ad_s[h*12+c]; }
        asrc[(size_t)n*8 + h] = sa;
        adst[(size_t)n*8 + h] = sd;
    }
}

// ---------------- 2a. degree count ----------------
__global__ void deg_count(const int* __restrict__ ei, int* __restrict__ deg)
{
    int e = blockIdx.x * 256 + threadIdx.x;
    int dst = ei[N_EDGES_C + e];
    atomicAdd(&deg[dst], 1);
}

// ---------------- 2b. exclusive scan over 65536 degrees (single block) ----------------
__global__ void scan_build(const int* __restrict__ deg, int* __restrict__ rowptr, int* __restrict__ cursor)
{
    __shared__ int sums[1024];
    int tid = threadIdx.x;
    int base = tid * 64;
    int s = 0;
    for (int j = 0; j < 64; j++) s += deg[base + j];
    sums[tid] = s;
    __syncthreads();
    for (int off = 1; off < 1024; off <<= 1) {
        int v = 0;
        if (tid >= off) v = sums[tid - off];
        __syncthreads();
        if (tid >= off) sums[tid] += v;
        __syncthreads();
    }
    int run = sums[tid] - s;   // exclusive prefix of this chunk
    for (int j = 0; j < 64; j++) {
        rowptr[base + j] = run;
        cursor[base + j] = run;
        run += deg[base + j];
    }
    if (tid == 1023) rowptr[65536] = sums[1023];
}

// ---------------- 2c. scatter edges into CSR by dst ----------------
__global__ void edge_scatter(const int* __restrict__ ei, int* __restrict__ cursor, int* __restrict__ csr_src)
{
    int e = blockIdx.x * 256 + threadIdx.x;
    int src = ei[e];
    int dst = ei[N_EDGES_C + e];
    int pos = atomicAdd(&cursor[dst], 1);
    csr_src[pos] = src;
}

// ---------------- 3. per-(node,head) online-softmax aggregation + BN + log_softmax ----------------
__global__ void gat_aggregate(const float* __restrict__ xp, const float* __restrict__ asrc,
                              const float* __restrict__ adst,
                              const int* __restrict__ rowptr, const int* __restrict__ csr_src,
                              const float* __restrict__ gat_bias, const float* __restrict__ bn_gamma,
                              const float* __restrict__ bn_beta, const float* __restrict__ bn_mean,
                              const float* __restrict__ bn_var, float* __restrict__ seq)
{
    int gid = blockIdx.x * 256 + threadIdx.x;
    int n = gid >> 3;
    int h = gid & 7;

    float adst_n = adst[(size_t)n*8 + h];
    // self-loop initializes the online softmax state
    float m = lrelu(asrc[(size_t)n*8 + h] + adst_n);
    float d = 1.0f;
    float acc[12];
    {
        const float4* xv = (const float4*)(xp + (size_t)n*96 + h*12);
        float4 a0 = xv[0], a1 = xv[1], a2 = xv[2];
        acc[0]=a0.x; acc[1]=a0.y; acc[2]=a0.z; acc[3]=a0.w;
        acc[4]=a1.x; acc[5]=a1.y; acc[6]=a1.z; acc[7]=a1.w;
        acc[8]=a2.x; acc[9]=a2.y; acc[10]=a2.z; acc[11]=a2.w;
    }
    int beg = rowptr[n], end = rowptr[n+1];
    for (int i = beg; i < end; i++) {
        int src = csr_src[i];
        float e = lrelu(asrc[(size_t)src*8 + h] + adst_n);
        float mn = fmaxf(m, e);
        float sc = expf(m - mn);
        float w  = expf(e - mn);
        m = mn;
        d = d * sc + w;
        const float4* sv = (const float4*)(xp + (size_t)src*96 + h*12);
        float4 b0 = sv[0], b1 = sv[1], b2 = sv[2];
        acc[0]=acc[0]*sc + w*b0.x; acc[1]=acc[1]*sc + w*b0.y; acc[2]=acc[2]*sc + w*b0.z; acc[3]=acc[3]*sc + w*b0.w;
        acc[4]=acc[4]*sc + w*b1.x; acc[5]=acc[5]*sc + w*b1.y; acc[6]=acc[6]*sc + w*b1.z; acc[7]=acc[7]*sc + w*b1.w;
        acc[8]=acc[8]*sc + w*b2.x; acc[9]=acc[9]*sc + w*b2.y; acc[10]=acc[10]*sc + w*b2.z; acc[11]=acc[11]*sc + w*b2.w;
    }
    float inv = 1.0f / (d + 1e-16f);
    float res[12];
    #pragma unroll
    for (int c = 0; c < 12; c++) {
        float v = acc[c] * inv;
        v += __shfl_xor(v, 1);
        v += __shfl_xor(v, 2);
        v += __shfl_xor(v, 4);
        res[c] = v * 0.125f;     // mean over 8 heads
    }
    if (h == 0) {
        float vals[12];
        float mx = -1e30f;
        #pragma unroll
        for (int c = 0; c < 12; c++) {
            float v = res[c] + gat_bias[c];
            v = (v - bn_mean[c]) * rsqrtf(bn_var[c] + 1e-5f) * bn_gamma[c] + bn_beta[c];
            vals[c] = v;
            mx = fmaxf(mx, v);
        }
        float sum = 0.f;
        #pragma unroll
        for (int c = 0; c < 12; c++) sum += expf(vals[c] - mx);
        float lse = logf(sum) + mx;
        #pragma unroll
        for (int c = 0; c < 12; c++) seq[(size_t)c * N_TOTAL_C + n] = vals[c] - lse;
    }
}

// ---------------- 4. X1 = seq(384x2048) @ w_ih1(128x2048)^T ----------------
__global__ void gemm_x1(const float* __restrict__ A, const float* __restrict__ B,
                        float* __restrict__ C, int K, int N)
{
    __shared__ float As[32][33], Bs[32][33];
    int tid = threadIdx.x;
    int tx = tid & 31, ty = tid >> 5;
    int bm = blockIdx.x * 32, bn = blockIdx.y * 32;
    float acc[4] = {0.f,0.f,0.f,0.f};
    for (int k0 = 0; k0 < K; k0 += 32) {
        #pragma unroll
        for (int i = 0; i < 4; i++) {
            int r = ty + i*8;
            As[r][tx] = A[(size_t)(bm + r) * K + k0 + tx];
            Bs[r][tx] = B[(size_t)(bn + r) * K + k0 + tx];
        }
        __syncthreads();
        #pragma unroll
        for (int kk = 0; kk < 32; kk++) {
            float bv = Bs[tx][kk];
            #pragma unroll
            for (int i = 0; i < 4; i++) acc[i] += As[ty + i*8][kk] * bv;
        }
        __syncthreads();
    }
    #pragma unroll
    for (int i = 0; i < 4; i++) C[(size_t)(bm + ty + i*8) * N + bn + tx] = acc[i];
}

// ---------------- 5. fused LSTM1(2048->32) + LSTM2(32->128), one block per batch ----------------
__global__ void lstm_fused(const float* __restrict__ X1, const float* __restrict__ w_hh1,
                           const float* __restrict__ b_ih1, const float* __restrict__ b_hh1,
                           const float* __restrict__ w_ih2, const float* __restrict__ w_hh2,
                           const float* __restrict__ b_ih2, const float* __restrict__ b_hh2,
                           float* __restrict__ H2)
{
    __shared__ float whh1[128*33];             // padded stride 33: kills 32-stride bank conflict
    __shared__ float b1s[128], b2s[512];
    __shared__ float h1[32], c1[32], h2[128], c2[128];
    __shared__ float g1s[128], g2s[512];
    int tid = threadIdx.x;
    int b = blockIdx.x;
    for (int i = tid; i < 128*32; i += 512) whh1[(i >> 5)*33 + (i & 31)] = w_hh1[i];
    if (tid < 128) b1s[tid] = b_ih1[tid] + b_hh1[tid];
    b2s[tid] = b_ih2[tid] + b_hh2[tid];
    if (tid < 32)  { h1[tid] = 0.f; c1[tid] = 0.f; }
    if (tid < 128) { h2[tid] = 0.f; c2[tid] = 0.f; }
    __syncthreads();

    for (int t = 0; t < 12; t++) {
        // LSTM1 gates
        if (tid < 128) {
            const float* wr = &whh1[tid * 33];
            float acc = X1[((size_t)t*32 + b)*128 + tid] + b1s[tid];
            #pragma unroll
            for (int k = 0; k < 32; k++) acc += h1[k] * wr[k];
            g1s[tid] = acc;
        }
        __syncthreads();
        if (tid < 32) {
            float ig = sigf(g1s[tid]), fg = sigf(g1s[32+tid]);
            float gg = tanhf(g1s[64+tid]), og = sigf(g1s[96+tid]);
            float cn = fg * c1[tid] + ig * gg;
            c1[tid] = cn;
            h1[tid] = og * tanhf(cn);
        }
        __syncthreads();
        // LSTM2 gates (512 threads, one gate each)
        {
            const float* wi = w_ih2 + (size_t)tid * 32;     // L2-resident
            float acc = b2s[tid];
            #pragma unroll
            for (int k = 0; k < 32; k++) acc += h1[k] * wi[k];
            const float4* wh = (const float4*)(w_hh2 + (size_t)tid * 128);
            #pragma unroll
            for (int k = 0; k < 32; k++) {
                float4 wv = wh[k];
                acc += h2[k*4+0]*wv.x + h2[k*4+1]*wv.y + h2[k*4+2]*wv.z + h2[k*4+3]*wv.w;
            }
            g2s[tid] = acc;
        }
        __syncthreads();
        if (tid < 128) {
            float ig = sigf(g2s[tid]), fg = sigf(g2s[128+tid]);
            float gg = tanhf(g2s[256+tid]), og = sigf(g2s[384+tid]);
            float cn = fg * c2[tid] + ig * gg;
            c2[tid] = cn;
            float hn = og * tanhf(cn);
            h2[tid] = hn;
            if (t >= 3) H2[((size_t)t*32 + b)*128 + tid] = hn;
        }
        __syncthreads();
    }
}

// ---------------- 6. out = H2[3:] (288x128) @ lin_w(2048x128)^T + lin_b, scattered epilogue ----------------
__global__ void gemm_out(const float* __restrict__ A, const float* __restrict__ B,
                         const float* __restrict__ bias, float* __restrict__ out)
{
    __shared__ float As[32][33], Bs[32][33];
    const int K = 128;
    int tid = threadIdx.x;
    int tx = tid & 31, ty = tid >> 5;
    int bm = blockIdx.x * 32, bn = blockIdx.y * 32;
    float acc[4] = {0.f,0.f,0.f,0.f};
    for (int k0 = 0; k0 < K; k0 += 32) {
        #pragma unroll
        for (int i = 0; i < 4; i++) {
            int r = ty + i*8;
            As[r][tx] = A[(size_t)(bm + r) * K + k0 + tx];
            Bs[r][tx] = B[(size_t)(bn + r) * K + k0 + tx];
        }
        __syncthreads();
        #pragma unroll
        for (int kk = 0; kk < 32; kk++) {
            float bv = Bs[tx][kk];
            #pragma unroll
            for (int i = 0; i < 4; i++) acc[i] += As[ty + i*8][kk] * bv;
        }
        __syncthreads();
    }
    int j = blockIdx.x;            // time slot within last 9 (rows are m = j*32 + b)
    int nn = bn + tx;
    float bv = bias[nn];
    #pragma unroll
    for (int i = 0; i < 4; i++) {
        int bb = ty + i*8;
        out[((size_t)bb * 2048 + nn) * 9 + j] = acc[i] + bv;
    }
}

extern "C" void kernel_launch(void* const* d_in, const int* in_sizes, int n_in,
                              void* d_out, int out_size, void* d_ws, size_t ws_size,
                              hipStream_t stream)
{
    const float* x        = (const float*)d_in[0];
    const int*   ei       = (const int*)  d_in[1];
    const float* W_gat    = (const float*)d_in[2];
    const float* a_src    = (const float*)d_in[3];
    const float* a_dst    = (const float*)d_in[4];
    const float* gat_bias = (const float*)d_in[5];
    const float* bn_gamma = (const float*)d_in[6];
    const float* bn_beta  = (const float*)d_in[7];
    const float* bn_mean  = (const float*)d_in[8];
    const float* bn_var   = (const float*)d_in[9];
    const float* w_ih1    = (const float*)d_in[10];
    const float* w_hh1    = (const float*)d_in[11];
    const float* b_ih1    = (const float*)d_in[12];
    const float* b_hh1    = (const float*)d_in[13];
    const float* w_ih2    = (const float*)d_in[14];
    const float* w_hh2    = (const float*)d_in[15];
    const float* b_ih2    = (const float*)d_in[16];
    const float* b_hh2    = (const float*)d_in[17];
    const float* lin_w    = (const float*)d_in[18];
    const float* lin_b    = (const float*)d_in[19];
    float* out = (float*)d_out;

    float* ws   = (float*)d_ws;
    float* xp   = ws;                       // 65536*96   = 6291456 floats
    float* asrc = xp   + 6291456;           // 524288
    float* adst = asrc + 524288;            // 524288
    float* seq  = adst + 524288;            // 12*65536   = 786432
    float* X1   = seq  + 786432;            // 384*128    = 49152
    float* H2   = X1   + 49152;             // 384*128    = 49152
    int* rowptr = (int*)(H2 + 49152);       // 65537
    int* cursor = rowptr + 65537;           // 65536
    int* deg    = cursor + 65536;           // 65536
    int* csr    = deg    + 65536;           // 1048576
    // total ~37.9 MB of d_ws

    hipMemsetAsync(deg, 0, 65536 * sizeof(int), stream);
    node_transform<<<256, 256, 0, stream>>>(x, W_gat, a_src, a_dst, xp, asrc, adst);
    deg_count   <<<4096, 256, 0, stream>>>(ei, deg);
    scan_build  <<<1, 1024, 0, stream>>>(deg, rowptr, cursor);
    edge_scatter<<<4096, 256, 0, stream>>>(ei, cursor, csr);
    gat_aggregate<<<2048, 256, 0, stream>>>(xp, asrc, adst, rowptr, csr,
                                            gat_bias, bn_gamma, bn_beta, bn_mean, bn_var, seq);
    gemm_x1<<<dim3(12, 4), 256, 0, stream>>>(seq, w_ih1, X1, 2048, 128);
    lstm_fused<<<32, 512, 0, stream>>>(X1, w_hh1, b_ih1, b_hh1, w_ih2, w_hh2, b_ih2, b_hh2, H2);
    gemm_out<<<dim3(9, 64), 256, 0, stream>>>(H2 + 96*128, lin_w, lin_b, out);
}

// Round 2
// 482.701 us; speedup vs baseline: 1.1249x; 1.1249x over previous
//
#include <hip/hip_runtime.h>
#include <math.h>

#define N_EDGES_C 1048576
#define N_TOTAL_C 65536

__device__ __forceinline__ float sigf(float x){ return 1.0f/(1.0f+expf(-x)); }
__device__ __forceinline__ float lrelu(float x){ return (x>=0.f)? x : 0.2f*x; }

// ---------------- 1. node transform: xp = x @ W_gat, asrc/adst ----------------
__global__ void node_transform(const float* __restrict__ x, const float* __restrict__ Wg,
                               const float* __restrict__ a_src, const float* __restrict__ a_dst,
                               float* __restrict__ xp, float* __restrict__ asrc, float* __restrict__ adst)
{
    __shared__ float Ws[12*96];
    __shared__ float as_s[96], ad_s[96];
    int tid = threadIdx.x;
    for (int i = tid; i < 1152; i += 256) Ws[i] = Wg[i];
    if (tid < 96) { as_s[tid] = a_src[tid]; ad_s[tid] = a_dst[tid]; }
    __syncthreads();
    int n = blockIdx.x * 256 + tid;
    const float4* xv = (const float4*)(x + (size_t)n * 12);
    float4 v0 = xv[0], v1 = xv[1], v2 = xv[2];
    float xr[12] = {v0.x,v0.y,v0.z,v0.w, v1.x,v1.y,v1.z,v1.w, v2.x,v2.y,v2.z,v2.w};
    float* xpr = xp + (size_t)n * 96;
    #pragma unroll
    for (int h = 0; h < 8; h++) {
        float xph[12];
        #pragma unroll
        for (int c = 0; c < 12; c++) {
            float acc = 0.f;
            #pragma unroll
            for (int k = 0; k < 12; k++) acc += xr[k] * Ws[k*96 + h*12 + c];
            xph[c] = acc;
        }
        float4* o = (float4*)(xpr + h*12);
        o[0] = make_float4(xph[0],xph[1],xph[2],xph[3]);
        o[1] = make_float4(xph[4],xph[5],xph[6],xph[7]);
        o[2] = make_float4(xph[8],xph[9],xph[10],xph[11]);
        float sa = 0.f, sd = 0.f;
        #pragma unroll
        for (int c = 0; c < 12; c++) { sa += xph[c]*as_s[h*12+c]; sd += xph[c]*ad_s[h*12+c]; }
        asrc[(size_t)n*8 + h] = sa;
        adst[(size_t)n*8 + h] = sd;
    }
}

// ---------------- 2a. degree count ----------------
__global__ void deg_count(const int* __restrict__ ei, int* __restrict__ deg)
{
    int e = blockIdx.x * 256 + threadIdx.x;
    int dst = ei[N_EDGES_C + e];
    atomicAdd(&deg[dst], 1);
}

// ---------------- 2b. exclusive scan over 65536 degrees (single block) ----------------
__global__ void scan_build(const int* __restrict__ deg, int* __restrict__ rowptr, int* __restrict__ cursor)
{
    __shared__ int sums[1024];
    int tid = threadIdx.x;
    int base = tid * 64;
    int s = 0;
    for (int j = 0; j < 64; j++) s += deg[base + j];
    sums[tid] = s;
    __syncthreads();
    for (int off = 1; off < 1024; off <<= 1) {
        int v = 0;
        if (tid >= off) v = sums[tid - off];
        __syncthreads();
        if (tid >= off) sums[tid] += v;
        __syncthreads();
    }
    int run = sums[tid] - s;   // exclusive prefix of this chunk
    for (int j = 0; j < 64; j++) {
        rowptr[base + j] = run;
        cursor[base + j] = run;
        run += deg[base + j];
    }
    if (tid == 1023) rowptr[65536] = sums[1023];
}

// ---------------- 2c. scatter edges into CSR by dst ----------------
__global__ void edge_scatter(const int* __restrict__ ei, int* __restrict__ cursor, int* __restrict__ csr_src)
{
    int e = blockIdx.x * 256 + threadIdx.x;
    int src = ei[e];
    int dst = ei[N_EDGES_C + e];
    int pos = atomicAdd(&cursor[dst], 1);
    csr_src[pos] = src;
}

// ---------------- 3. per-(node,head) online-softmax aggregation + BN + log_softmax ----------------
__global__ void gat_aggregate(const float* __restrict__ xp, const float* __restrict__ asrc,
                              const float* __restrict__ adst,
                              const int* __restrict__ rowptr, const int* __restrict__ csr_src,
                              const float* __restrict__ gat_bias, const float* __restrict__ bn_gamma,
                              const float* __restrict__ bn_beta, const float* __restrict__ bn_mean,
                              const float* __restrict__ bn_var, float* __restrict__ seq)
{
    int gid = blockIdx.x * 256 + threadIdx.x;
    int n = gid >> 3;
    int h = gid & 7;

    float adst_n = adst[(size_t)n*8 + h];
    // self-loop initializes the online softmax state
    float m = lrelu(asrc[(size_t)n*8 + h] + adst_n);
    float d = 1.0f;
    float acc[12];
    {
        const float4* xv = (const float4*)(xp + (size_t)n*96 + h*12);
        float4 a0 = xv[0], a1 = xv[1], a2 = xv[2];
        acc[0]=a0.x; acc[1]=a0.y; acc[2]=a0.z; acc[3]=a0.w;
        acc[4]=a1.x; acc[5]=a1.y; acc[6]=a1.z; acc[7]=a1.w;
        acc[8]=a2.x; acc[9]=a2.y; acc[10]=a2.z; acc[11]=a2.w;
    }
    int beg = rowptr[n], end = rowptr[n+1];
    for (int i = beg; i < end; i++) {
        int src = csr_src[i];
        float e = lrelu(asrc[(size_t)src*8 + h] + adst_n);
        float mn = fmaxf(m, e);
        float sc = expf(m - mn);
        float w  = expf(e - mn);
        m = mn;
        d = d * sc + w;
        const float4* sv = (const float4*)(xp + (size_t)src*96 + h*12);
        float4 b0 = sv[0], b1 = sv[1], b2 = sv[2];
        acc[0]=acc[0]*sc + w*b0.x; acc[1]=acc[1]*sc + w*b0.y; acc[2]=acc[2]*sc + w*b0.z; acc[3]=acc[3]*sc + w*b0.w;
        acc[4]=acc[4]*sc + w*b1.x; acc[5]=acc[5]*sc + w*b1.y; acc[6]=acc[6]*sc + w*b1.z; acc[7]=acc[7]*sc + w*b1.w;
        acc[8]=acc[8]*sc + w*b2.x; acc[9]=acc[9]*sc + w*b2.y; acc[10]=acc[10]*sc + w*b2.z; acc[11]=acc[11]*sc + w*b2.w;
    }
    float inv = 1.0f / (d + 1e-16f);
    float res[12];
    #pragma unroll
    for (int c = 0; c < 12; c++) {
        float v = acc[c] * inv;
        v += __shfl_xor(v, 1);
        v += __shfl_xor(v, 2);
        v += __shfl_xor(v, 4);
        res[c] = v * 0.125f;     // mean over 8 heads
    }
    if (h == 0) {
        float vals[12];
        float mx = -1e30f;
        #pragma unroll
        for (int c = 0; c < 12; c++) {
            float v = res[c] + gat_bias[c];
            v = (v - bn_mean[c]) * rsqrtf(bn_var[c] + 1e-5f) * bn_gamma[c] + bn_beta[c];
            vals[c] = v;
            mx = fmaxf(mx, v);
        }
        float sum = 0.f;
        #pragma unroll
        for (int c = 0; c < 12; c++) sum += expf(vals[c] - mx);
        float lse = logf(sum) + mx;
        #pragma unroll
        for (int c = 0; c < 12; c++) seq[(size_t)c * N_TOTAL_C + n] = vals[c] - lse;
    }
}

// ---------------- 4. X1 = seq(384x2048) @ w_ih1(128x2048)^T, split-K x16 ----------------
// grid (12 Mtiles, 4 Ntiles, 16 Ksplits); X1 must be zeroed first; fp32 atomicAdd partials.
__global__ void gemm_x1(const float* __restrict__ A, const float* __restrict__ B,
                        float* __restrict__ C)
{
    __shared__ float As[32][33], Bs[32][33];
    const int K = 2048, N = 128;
    int tid = threadIdx.x;
    int tx = tid & 31, ty = tid >> 5;
    int bm = blockIdx.x * 32, bn = blockIdx.y * 32;
    int kbase = blockIdx.z * 128;
    float acc[4] = {0.f,0.f,0.f,0.f};
    for (int kk = 0; kk < 128; kk += 32) {
        int k0 = kbase + kk;
        #pragma unroll
        for (int i = 0; i < 4; i++) {
            int r = ty + i*8;
            As[r][tx] = A[(size_t)(bm + r) * K + k0 + tx];
            Bs[r][tx] = B[(size_t)(bn + r) * K + k0 + tx];
        }
        __syncthreads();
        #pragma unroll
        for (int k = 0; k < 32; k++) {
            float bv = Bs[tx][k];
            #pragma unroll
            for (int i = 0; i < 4; i++) acc[i] += As[ty + i*8][k] * bv;
        }
        __syncthreads();
    }
    #pragma unroll
    for (int i = 0; i < 4; i++)
        atomicAdd(&C[(size_t)(bm + ty + i*8) * N + bn + tx], acc[i]);
}

// ---------------- 5. fused LSTM1(2048->32) + LSTM2(32->128) ----------------
// One block per batch. w_ih2/w_hh2 rows preloaded into REGISTERS (time-invariant,
// ~160 VGPR/thread) -> no per-timestep global traffic on the recurrence path.
__global__ __launch_bounds__(512, 2)
void lstm_fused(const float* __restrict__ X1, const float* __restrict__ w_hh1,
                const float* __restrict__ b_ih1, const float* __restrict__ b_hh1,
                const float* __restrict__ w_ih2, const float* __restrict__ w_hh2,
                const float* __restrict__ b_ih2, const float* __restrict__ b_hh2,
                float* __restrict__ H2)
{
    __shared__ float whh1[128*33];             // padded stride 33: (tid+k)%32 -> 2-way only (free)
    __shared__ float b1s[128];
    __shared__ float h1[32], c1[32];
    __shared__ float4 h2v[32];                 // h2 as float4[32]
    __shared__ float c2[128];
    __shared__ float g1s[128], g2s[512];
    int tid = threadIdx.x;
    int b = blockIdx.x;

    // --- time-invariant weight preload into registers ---
    float wih[32];
    {
        const float4* wi = (const float4*)(w_ih2 + (size_t)tid * 32);
        #pragma unroll
        for (int k = 0; k < 8; k++) {
            float4 v = wi[k];
            wih[k*4+0]=v.x; wih[k*4+1]=v.y; wih[k*4+2]=v.z; wih[k*4+3]=v.w;
        }
    }
    float4 whh[32];
    {
        const float4* wh = (const float4*)(w_hh2 + (size_t)tid * 128);
        #pragma unroll
        for (int k = 0; k < 32; k++) whh[k] = wh[k];
    }
    float b2 = b_ih2[tid] + b_hh2[tid];

    for (int i = tid; i < 128*32; i += 512) whh1[(i >> 5)*33 + (i & 31)] = w_hh1[i];
    if (tid < 128) b1s[tid] = b_ih1[tid] + b_hh1[tid];
    if (tid < 32)  { h1[tid] = 0.f; c1[tid] = 0.f; h2v[tid] = make_float4(0.f,0.f,0.f,0.f); }
    if (tid < 128) { c2[tid] = 0.f; }
    __syncthreads();

    for (int t = 0; t < 12; t++) {
        // Phase 1 (overlapped): ALL threads start the hh2 matvec from registers;
        // threads <128 additionally compute the LSTM1 gate.
        float a0 = 0.f, a1 = 0.f, a2 = 0.f, a3 = 0.f;
        #pragma unroll
        for (int k = 0; k < 32; k += 4) {
            float4 hv0 = h2v[k+0], hv1 = h2v[k+1], hv2 = h2v[k+2], hv3 = h2v[k+3];
            float4 w0 = whh[k+0], w1 = whh[k+1], w2 = whh[k+2], w3 = whh[k+3];
            a0 += hv0.x*w0.x + hv0.y*w0.y + hv0.z*w0.z + hv0.w*w0.w;
            a1 += hv1.x*w1.x + hv1.y*w1.y + hv1.z*w1.z + hv1.w*w1.w;
            a2 += hv2.x*w2.x + hv2.y*w2.y + hv2.z*w2.z + hv2.w*w2.w;
            a3 += hv3.x*w3.x + hv3.y*w3.y + hv3.z*w3.z + hv3.w*w3.w;
        }
        float acc2 = b2 + a0 + a1 + a2 + a3;

        if (tid < 128) {
            const float* wr = &whh1[tid * 33];
            float acc = X1[((size_t)t*32 + b)*128 + tid] + b1s[tid];
            #pragma unroll
            for (int k = 0; k < 32; k++) acc += h1[k] * wr[k];
            g1s[tid] = acc;
        }
        __syncthreads();
        // Phase 2: LSTM1 activation
        if (tid < 32) {
            float ig = sigf(g1s[tid]), fg = sigf(g1s[32+tid]);
            float gg = tanhf(g1s[64+tid]), og = sigf(g1s[96+tid]);
            float cn = fg * c1[tid] + ig * gg;
            c1[tid] = cn;
            h1[tid] = og * tanhf(cn);
        }
        __syncthreads();
        // Phase 3: finish LSTM2 gate with ih2 contribution (h1 now fresh)
        {
            #pragma unroll
            for (int k = 0; k < 32; k++) acc2 += h1[k] * wih[k];
            g2s[tid] = acc2;
        }
        __syncthreads();
        // Phase 4: LSTM2 activation + publish h2
        if (tid < 128) {
            float ig = sigf(g2s[tid]), fg = sigf(g2s[128+tid]);
            float gg = tanhf(g2s[256+tid]), og = sigf(g2s[384+tid]);
            float cn = fg * c2[tid] + ig * gg;
            c2[tid] = cn;
            float hn = og * tanhf(cn);
            ((float*)h2v)[tid] = hn;
            if (t >= 3) H2[((size_t)t*32 + b)*128 + tid] = hn;
        }
        __syncthreads();
    }
}

// ---------------- 6. out = H2[3:] (288x128) @ lin_w(2048x128)^T + lin_b ----------------
__global__ void gemm_out(const float* __restrict__ A, const float* __restrict__ B,
                         const float* __restrict__ bias, float* __restrict__ out)
{
    __shared__ float As[32][33], Bs[32][33];
    const int K = 128;
    int tid = threadIdx.x;
    int tx = tid & 31, ty = tid >> 5;
    int bm = blockIdx.x * 32, bn = blockIdx.y * 32;
    float acc[4] = {0.f,0.f,0.f,0.f};
    for (int k0 = 0; k0 < K; k0 += 32) {
        #pragma unroll
        for (int i = 0; i < 4; i++) {
            int r = ty + i*8;
            As[r][tx] = A[(size_t)(bm + r) * K + k0 + tx];
            Bs[r][tx] = B[(size_t)(bn + r) * K + k0 + tx];
        }
        __syncthreads();
        #pragma unroll
        for (int kk = 0; kk < 32; kk++) {
            float bv = Bs[tx][kk];
            #pragma unroll
            for (int i = 0; i < 4; i++) acc[i] += As[ty + i*8][kk] * bv;
        }
        __syncthreads();
    }
    int j = blockIdx.x;            // time slot within last 9 (rows are m = j*32 + b)
    int nn = bn + tx;
    float bv = bias[nn];
    #pragma unroll
    for (int i = 0; i < 4; i++) {
        int bb = ty + i*8;
        out[((size_t)bb * 2048 + nn) * 9 + j] = acc[i] + bv;
    }
}

extern "C" void kernel_launch(void* const* d_in, const int* in_sizes, int n_in,
                              void* d_out, int out_size, void* d_ws, size_t ws_size,
                              hipStream_t stream)
{
    const float* x        = (const float*)d_in[0];
    const int*   ei       = (const int*)  d_in[1];
    const float* W_gat    = (const float*)d_in[2];
    const float* a_src    = (const float*)d_in[3];
    const float* a_dst    = (const float*)d_in[4];
    const float* gat_bias = (const float*)d_in[5];
    const float* bn_gamma = (const float*)d_in[6];
    const float* bn_beta  = (const float*)d_in[7];
    const float* bn_mean  = (const float*)d_in[8];
    const float* bn_var   = (const float*)d_in[9];
    const float* w_ih1    = (const float*)d_in[10];
    const float* w_hh1    = (const float*)d_in[11];
    const float* b_ih1    = (const float*)d_in[12];
    const float* b_hh1    = (const float*)d_in[13];
    const float* w_ih2    = (const float*)d_in[14];
    const float* w_hh2    = (const float*)d_in[15];
    const float* b_ih2    = (const float*)d_in[16];
    const float* b_hh2    = (const float*)d_in[17];
    const float* lin_w    = (const float*)d_in[18];
    const float* lin_b    = (const float*)d_in[19];
    float* out = (float*)d_out;

    float* ws   = (float*)d_ws;
    float* xp   = ws;                       // 65536*96   = 6291456 floats
    float* asrc = xp   + 6291456;           // 524288
    float* adst = asrc + 524288;            // 524288
    float* seq  = adst + 524288;            // 12*65536   = 786432
    float* X1   = seq  + 786432;            // 384*128    = 49152
    float* H2   = X1   + 49152;             // 384*128    = 49152
    int* rowptr = (int*)(H2 + 49152);       // 65537
    int* cursor = rowptr + 65537;           // 65536
    int* deg    = cursor + 65536;           // 65536
    int* csr    = deg    + 65536;           // 1048576
    // total ~37.9 MB of d_ws

    hipMemsetAsync(deg, 0, 65536 * sizeof(int), stream);
    hipMemsetAsync(X1, 0, 49152 * sizeof(float), stream);
    node_transform<<<256, 256, 0, stream>>>(x, W_gat, a_src, a_dst, xp, asrc, adst);
    deg_count   <<<4096, 256, 0, stream>>>(ei, deg);
    scan_build  <<<1, 1024, 0, stream>>>(deg, rowptr, cursor);
    edge_scatter<<<4096, 256, 0, stream>>>(ei, cursor, csr);
    gat_aggregate<<<2048, 256, 0, stream>>>(xp, asrc, adst, rowptr, csr,
                                            gat_bias, bn_gamma, bn_beta, bn_mean, bn_var, seq);
    gemm_x1<<<dim3(12, 4, 16), 256, 0, stream>>>(seq, w_ih1, X1);
    lstm_fused<<<32, 512, 0, stream>>>(X1, w_hh1, b_ih1, b_hh1, w_ih2, w_hh2, b_ih2, b_hh2, H2);
    gemm_out<<<dim3(9, 64), 256, 0, stream>>>(H2 + 96*128, lin_w, lin_b, out);
}

// Round 3
// 380.352 us; speedup vs baseline: 1.4276x; 1.2691x over previous
//
#include <hip/hip_runtime.h>
#include <math.h>

#define N_EDGES_C 1048576
#define N_TOTAL_C 65536

typedef _Float16 h2v __attribute__((ext_vector_type(2)));
typedef _Float16 h4v __attribute__((ext_vector_type(4)));

#if defined(__has_builtin)
#if __has_builtin(__builtin_amdgcn_fdot2)
#define HAS_FDOT2 1
#endif
#endif

__device__ __forceinline__ float fdot2(h2v a, h2v b, float c) {
#ifdef HAS_FDOT2
    return __builtin_amdgcn_fdot2(a, b, c, false);
#else
    return c + (float)a.x * (float)b.x + (float)a.y * (float)b.y;
#endif
}

__device__ __forceinline__ float sigf(float x){ return 1.0f/(1.0f+expf(-x)); }
__device__ __forceinline__ float lrelu(float x){ return (x>=0.f)? x : 0.2f*x; }

// ---------------- 1. node transform: xp(fp16) = x @ W_gat, asrc/adst(fp32) ----------------
__global__ void node_transform(const float* __restrict__ x, const float* __restrict__ Wg,
                               const float* __restrict__ a_src, const float* __restrict__ a_dst,
                               _Float16* __restrict__ xph, float* __restrict__ asrc, float* __restrict__ adst)
{
    __shared__ float Ws[12*96];
    __shared__ float as_s[96], ad_s[96];
    int tid = threadIdx.x;
    for (int i = tid; i < 1152; i += 256) Ws[i] = Wg[i];
    if (tid < 96) { as_s[tid] = a_src[tid]; ad_s[tid] = a_dst[tid]; }
    __syncthreads();
    int n = blockIdx.x * 256 + tid;
    const float4* xv = (const float4*)(x + (size_t)n * 12);
    float4 v0 = xv[0], v1 = xv[1], v2 = xv[2];
    float xr[12] = {v0.x,v0.y,v0.z,v0.w, v1.x,v1.y,v1.z,v1.w, v2.x,v2.y,v2.z,v2.w};
    _Float16* xpr = xph + (size_t)n * 96;
    #pragma unroll
    for (int h = 0; h < 8; h++) {
        float xp_[12];
        #pragma unroll
        for (int c = 0; c < 12; c++) {
            float acc = 0.f;
            #pragma unroll
            for (int k = 0; k < 12; k++) acc += xr[k] * Ws[k*96 + h*12 + c];
            xp_[c] = acc;
        }
        h4v* o = (h4v*)(xpr + h*12);      // offset h*24 B: 8-byte aligned
        #pragma unroll
        for (int j = 0; j < 3; j++) {
            h4v t;
            t.x = (_Float16)xp_[j*4+0]; t.y = (_Float16)xp_[j*4+1];
            t.z = (_Float16)xp_[j*4+2]; t.w = (_Float16)xp_[j*4+3];
            o[j] = t;
        }
        float sa = 0.f, sd = 0.f;
        #pragma unroll
        for (int c = 0; c < 12; c++) { sa += xp_[c]*as_s[h*12+c]; sd += xp_[c]*ad_s[h*12+c]; }
        asrc[(size_t)n*8 + h] = sa;
        adst[(size_t)n*8 + h] = sd;
    }
}

// ---------------- 2a. degree count ----------------
__global__ void deg_count(const int* __restrict__ ei, int* __restrict__ deg)
{
    int e = blockIdx.x * 256 + threadIdx.x;
    int dst = ei[N_EDGES_C + e];
    atomicAdd(&deg[dst], 1);
}

// ---------------- 2b. exclusive scan over 65536 degrees (single block) ----------------
__global__ void scan_build(const int* __restrict__ deg, int* __restrict__ rowptr, int* __restrict__ cursor)
{
    __shared__ int sums[1024];
    int tid = threadIdx.x;
    int base = tid * 64;
    int s = 0;
    for (int j = 0; j < 64; j++) s += deg[base + j];
    sums[tid] = s;
    __syncthreads();
    for (int off = 1; off < 1024; off <<= 1) {
        int v = 0;
        if (tid >= off) v = sums[tid - off];
        __syncthreads();
        if (tid >= off) sums[tid] += v;
        __syncthreads();
    }
    int run = sums[tid] - s;   // exclusive prefix of this chunk
    for (int j = 0; j < 64; j++) {
        rowptr[base + j] = run;
        cursor[base + j] = run;
        run += deg[base + j];
    }
    if (tid == 1023) rowptr[65536] = sums[1023];
}

// ---------------- 2c. scatter edges into CSR by dst ----------------
__global__ void edge_scatter(const int* __restrict__ ei, int* __restrict__ cursor, int* __restrict__ csr_src)
{
    int e = blockIdx.x * 256 + threadIdx.x;
    int src = ei[e];
    int dst = ei[N_EDGES_C + e];
    int pos = atomicAdd(&cursor[dst], 1);
    csr_src[pos] = src;
}

// ---------------- 3. per-(node,head) online-softmax aggregation + BN + log_softmax ----------------
__global__ void gat_aggregate(const _Float16* __restrict__ xph, const float* __restrict__ asrc,
                              const float* __restrict__ adst,
                              const int* __restrict__ rowptr, const int* __restrict__ csr_src,
                              const float* __restrict__ gat_bias, const float* __restrict__ bn_gamma,
                              const float* __restrict__ bn_beta, const float* __restrict__ bn_mean,
                              const float* __restrict__ bn_var, float* __restrict__ seq)
{
    int gid = blockIdx.x * 256 + threadIdx.x;
    int n = gid >> 3;
    int h = gid & 7;

    float adst_n = adst[(size_t)n*8 + h];
    // self-loop initializes the online softmax state
    float m = lrelu(asrc[(size_t)n*8 + h] + adst_n);
    float d = 1.0f;
    float acc[12];
    {
        const h4v* xv = (const h4v*)(xph + (size_t)n*96 + h*12);
        h4v a0 = xv[0], a1 = xv[1], a2 = xv[2];
        acc[0]=(float)a0.x; acc[1]=(float)a0.y; acc[2]=(float)a0.z; acc[3]=(float)a0.w;
        acc[4]=(float)a1.x; acc[5]=(float)a1.y; acc[6]=(float)a1.z; acc[7]=(float)a1.w;
        acc[8]=(float)a2.x; acc[9]=(float)a2.y; acc[10]=(float)a2.z; acc[11]=(float)a2.w;
    }
    int beg = rowptr[n], end = rowptr[n+1];
    for (int i = beg; i < end; i++) {
        int src = csr_src[i];
        float e = lrelu(asrc[(size_t)src*8 + h] + adst_n);
        float mn = fmaxf(m, e);
        float sc = expf(m - mn);
        float w  = expf(e - mn);
        m = mn;
        d = d * sc + w;
        const h4v* sv = (const h4v*)(xph + (size_t)src*96 + h*12);
        h4v b0 = sv[0], b1 = sv[1], b2 = sv[2];
        acc[0]=acc[0]*sc + w*(float)b0.x; acc[1]=acc[1]*sc + w*(float)b0.y; acc[2]=acc[2]*sc + w*(float)b0.z; acc[3]=acc[3]*sc + w*(float)b0.w;
        acc[4]=acc[4]*sc + w*(float)b1.x; acc[5]=acc[5]*sc + w*(float)b1.y; acc[6]=acc[6]*sc + w*(float)b1.z; acc[7]=acc[7]*sc + w*(float)b1.w;
        acc[8]=acc[8]*sc + w*(float)b2.x; acc[9]=acc[9]*sc + w*(float)b2.y; acc[10]=acc[10]*sc + w*(float)b2.z; acc[11]=acc[11]*sc + w*(float)b2.w;
    }
    float inv = 1.0f / (d + 1e-16f);
    float res[12];
    #pragma unroll
    for (int c = 0; c < 12; c++) {
        float v = acc[c] * inv;
        v += __shfl_xor(v, 1);
        v += __shfl_xor(v, 2);
        v += __shfl_xor(v, 4);
        res[c] = v * 0.125f;     // mean over 8 heads
    }
    if (h == 0) {
        float vals[12];
        float mx = -1e30f;
        #pragma unroll
        for (int c = 0; c < 12; c++) {
            float v = res[c] + gat_bias[c];
            v = (v - bn_mean[c]) * rsqrtf(bn_var[c] + 1e-5f) * bn_gamma[c] + bn_beta[c];
            vals[c] = v;
            mx = fmaxf(mx, v);
        }
        float sum = 0.f;
        #pragma unroll
        for (int c = 0; c < 12; c++) sum += expf(vals[c] - mx);
        float lse = logf(sum) + mx;
        #pragma unroll
        for (int c = 0; c < 12; c++) seq[(size_t)c * N_TOTAL_C + n] = vals[c] - lse;
    }
}

// ---------------- 4. X1 = seq(384x2048) @ w_ih1(128x2048)^T, split-K x16 ----------------
__global__ void gemm_x1(const float* __restrict__ A, const float* __restrict__ B,
                        float* __restrict__ C)
{
    __shared__ float As[32][33], Bs[32][33];
    const int K = 2048, N = 128;
    int tid = threadIdx.x;
    int tx = tid & 31, ty = tid >> 5;
    int bm = blockIdx.x * 32, bn = blockIdx.y * 32;
    int kbase = blockIdx.z * 128;
    float acc[4] = {0.f,0.f,0.f,0.f};
    for (int kk = 0; kk < 128; kk += 32) {
        int k0 = kbase + kk;
        #pragma unroll
        for (int i = 0; i < 4; i++) {
            int r = ty + i*8;
            As[r][tx] = A[(size_t)(bm + r) * K + k0 + tx];
            Bs[r][tx] = B[(size_t)(bn + r) * K + k0 + tx];
        }
        __syncthreads();
        #pragma unroll
        for (int k = 0; k < 32; k++) {
            float bv = Bs[tx][k];
            #pragma unroll
            for (int i = 0; i < 4; i++) acc[i] += As[ty + i*8][k] * bv;
        }
        __syncthreads();
    }
    #pragma unroll
    for (int i = 0; i < 4; i++)
        atomicAdd(&C[(size_t)(bm + ty + i*8) * N + bn + tx], acc[i]);
}

// ---------------- 5. fused LSTM1(2048->32) + LSTM2(32->128) ----------------
// One block per batch. LSTM2 weights held as fp16 half2 in REGISTERS
// (64+16 VGPR -> cannot spill at 256-VGPR cap; round-2's fp32x160 spilled).
// Dots via v_dot2_f32_f16, fp32 accumulate. Zero per-step global weight traffic.
__global__ __launch_bounds__(512)
void lstm_fused(const float* __restrict__ X1, const float* __restrict__ w_hh1,
                const float* __restrict__ b_ih1, const float* __restrict__ b_hh1,
                const float* __restrict__ w_ih2, const float* __restrict__ w_hh2,
                const float* __restrict__ b_ih2, const float* __restrict__ b_hh2,
                float* __restrict__ H2)
{
    __shared__ float whh1[128*33];             // padded stride 33
    __shared__ float b1s[128];
    __shared__ float h1[32], c1[32];
    __shared__ __align__(16) _Float16 h1s[32]; // h1 as fp16 for dot2
    __shared__ __align__(16) _Float16 h2s[128];// h2 as fp16 for dot2
    __shared__ float c2[128];
    __shared__ float g1s[128], g2s[512];
    int tid = threadIdx.x;
    int b = blockIdx.x;

    // --- time-invariant weight preload into registers (fp16 pairs) ---
    h2v whh[64];
    {
        const float2* wh = (const float2*)(w_hh2 + (size_t)tid * 128);
        #pragma unroll
        for (int k = 0; k < 64; k++) {
            float2 v = wh[k];
            h2v t; t.x = (_Float16)v.x; t.y = (_Float16)v.y;
            whh[k] = t;
        }
    }
    h2v wih[16];
    {
        const float2* wi = (const float2*)(w_ih2 + (size_t)tid * 32);
        #pragma unroll
        for (int k = 0; k < 16; k++) {
            float2 v = wi[k];
            h2v t; t.x = (_Float16)v.x; t.y = (_Float16)v.y;
            wih[k] = t;
        }
    }
    float b2 = b_ih2[tid] + b_hh2[tid];

    for (int i = tid; i < 128*32; i += 512) whh1[(i >> 5)*33 + (i & 31)] = w_hh1[i];
    if (tid < 128) b1s[tid] = b_ih1[tid] + b_hh1[tid];
    if (tid < 32)  { h1[tid] = 0.f; c1[tid] = 0.f; h1s[tid] = (_Float16)0.f; }
    if (tid < 128) { c2[tid] = 0.f; h2s[tid] = (_Float16)0.f; }
    __syncthreads();

    for (int t = 0; t < 12; t++) {
        // Phase 1: all 512 threads run the hh2 matvec from registers;
        // threads <128 additionally compute the LSTM1 gate.
        float p0 = b2, p1 = 0.f, p2 = 0.f, p3 = 0.f;
        #pragma unroll
        for (int j = 0; j < 16; j++) {
            float4 f = ((const float4*)h2s)[j];   // 8 halfs per ds_read_b128
            p0 = fdot2(__builtin_bit_cast(h2v, f.x), whh[j*4+0], p0);
            p1 = fdot2(__builtin_bit_cast(h2v, f.y), whh[j*4+1], p1);
            p2 = fdot2(__builtin_bit_cast(h2v, f.z), whh[j*4+2], p2);
            p3 = fdot2(__builtin_bit_cast(h2v, f.w), whh[j*4+3], p3);
        }
        float acc2 = (p0 + p1) + (p2 + p3);

        if (tid < 128) {
            const float* wr = &whh1[tid * 33];
            float acc = X1[((size_t)t*32 + b)*128 + tid] + b1s[tid];
            #pragma unroll
            for (int k = 0; k < 32; k++) acc += h1[k] * wr[k];
            g1s[tid] = acc;
        }
        __syncthreads();
        // Phase 2: LSTM1 activation
        if (tid < 32) {
            float ig = sigf(g1s[tid]), fg = sigf(g1s[32+tid]);
            float gg = tanhf(g1s[64+tid]), og = sigf(g1s[96+tid]);
            float cn = fg * c1[tid] + ig * gg;
            c1[tid] = cn;
            float hn = og * tanhf(cn);
            h1[tid] = hn;
            h1s[tid] = (_Float16)hn;
        }
        __syncthreads();
        // Phase 3: finish LSTM2 gate with ih2 contribution (h1 now fresh)
        {
            float q0 = 0.f, q1 = 0.f, q2 = 0.f, q3 = 0.f;
            #pragma unroll
            for (int j = 0; j < 4; j++) {
                float4 f = ((const float4*)h1s)[j];
                q0 = fdot2(__builtin_bit_cast(h2v, f.x), wih[j*4+0], q0);
                q1 = fdot2(__builtin_bit_cast(h2v, f.y), wih[j*4+1], q1);
                q2 = fdot2(__builtin_bit_cast(h2v, f.z), wih[j*4+2], q2);
                q3 = fdot2(__builtin_bit_cast(h2v, f.w), wih[j*4+3], q3);
            }
            g2s[tid] = acc2 + (q0 + q1) + (q2 + q3);
        }
        __syncthreads();
        // Phase 4: LSTM2 activation + publish h2
        if (tid < 128) {
            float ig = sigf(g2s[tid]), fg = sigf(g2s[128+tid]);
            float gg = tanhf(g2s[256+tid]), og = sigf(g2s[384+tid]);
            float cn = fg * c2[tid] + ig * gg;
            c2[tid] = cn;
            float hn = og * tanhf(cn);
            h2s[tid] = (_Float16)hn;
            if (t >= 3) H2[((size_t)t*32 + b)*128 + tid] = hn;
        }
        __syncthreads();
    }
}

// ---------------- 6. out = H2[3:] (288x128) @ lin_w(2048x128)^T + lin_b ----------------
__global__ void gemm_out(const float* __restrict__ A, const float* __restrict__ B,
                         const float* __restrict__ bias, float* __restrict__ out)
{
    __shared__ float As[32][33], Bs[32][33];
    const int K = 128;
    int tid = threadIdx.x;
    int tx = tid & 31, ty = tid >> 5;
    int bm = blockIdx.x * 32, bn = blockIdx.y * 32;
    float acc[4] = {0.f,0.f,0.f,0.f};
    for (int k0 = 0; k0 < K; k0 += 32) {
        #pragma unroll
        for (int i = 0; i < 4; i++) {
            int r = ty + i*8;
            As[r][tx] = A[(size_t)(bm + r) * K + k0 + tx];
            Bs[r][tx] = B[(size_t)(bn + r) * K + k0 + tx];
        }
        __syncthreads();
        #pragma unroll
        for (int kk = 0; kk < 32; kk++) {
            float bv = Bs[tx][kk];
            #pragma unroll
            for (int i = 0; i < 4; i++) acc[i] += As[ty + i*8][kk] * bv;
        }
        __syncthreads();
    }
    int j = blockIdx.x;            // time slot within last 9 (rows are m = j*32 + b)
    int nn = bn + tx;
    float bv = bias[nn];
    #pragma unroll
    for (int i = 0; i < 4; i++) {
        int bb = ty + i*8;
        out[((size_t)bb * 2048 + nn) * 9 + j] = acc[i] + bv;
    }
}

extern "C" void kernel_launch(void* const* d_in, const int* in_sizes, int n_in,
                              void* d_out, int out_size, void* d_ws, size_t ws_size,
                              hipStream_t stream)
{
    const float* x        = (const float*)d_in[0];
    const int*   ei       = (const int*)  d_in[1];
    const float* W_gat    = (const float*)d_in[2];
    const float* a_src    = (const float*)d_in[3];
    const float* a_dst    = (const float*)d_in[4];
    const float* gat_bias = (const float*)d_in[5];
    const float* bn_gamma = (const float*)d_in[6];
    const float* bn_beta  = (const float*)d_in[7];
    const float* bn_mean  = (const float*)d_in[8];
    const float* bn_var   = (const float*)d_in[9];
    const float* w_ih1    = (const float*)d_in[10];
    const float* w_hh1    = (const float*)d_in[11];
    const float* b_ih1    = (const float*)d_in[12];
    const float* b_hh1    = (const float*)d_in[13];
    const float* w_ih2    = (const float*)d_in[14];
    const float* w_hh2    = (const float*)d_in[15];
    const float* b_ih2    = (const float*)d_in[16];
    const float* b_hh2    = (const float*)d_in[17];
    const float* lin_w    = (const float*)d_in[18];
    const float* lin_b    = (const float*)d_in[19];
    float* out = (float*)d_out;

    float* ws = (float*)d_ws;
    _Float16* xph = (_Float16*)ws;          // 6291456 halfs = 3145728 float slots
    float* asrc = ws   + 3145728;           // 524288
    float* adst = asrc + 524288;            // 524288
    float* seq  = adst + 524288;            // 12*65536 = 786432
    float* X1   = seq  + 786432;            // 384*128  = 49152
    float* H2   = X1   + 49152;             // 384*128  = 49152
    int* rowptr = (int*)(H2 + 49152);       // 65537
    int* cursor = rowptr + 65537;           // 65536
    int* deg    = cursor + 65536;           // 65536
    int* csr    = deg    + 65536;           // 1048576
    // total ~25.3 MB of d_ws

    hipMemsetAsync(deg, 0, 65536 * sizeof(int), stream);
    hipMemsetAsync(X1, 0, 49152 * sizeof(float), stream);
    node_transform<<<256, 256, 0, stream>>>(x, W_gat, a_src, a_dst, xph, asrc, adst);
    deg_count   <<<4096, 256, 0, stream>>>(ei, deg);
    scan_build  <<<1, 1024, 0, stream>>>(deg, rowptr, cursor);
    edge_scatter<<<4096, 256, 0, stream>>>(ei, cursor, csr);
    gat_aggregate<<<2048, 256, 0, stream>>>(xph, asrc, adst, rowptr, csr,
                                            gat_bias, bn_gamma, bn_beta, bn_mean, bn_var, seq);
    gemm_x1<<<dim3(12, 4, 16), 256, 0, stream>>>(seq, w_ih1, X1);
    lstm_fused<<<32, 512, 0, stream>>>(X1, w_hh1, b_ih1, b_hh1, w_ih2, w_hh2, b_ih2, b_hh2, H2);
    gemm_out<<<dim3(9, 64), 256, 0, stream>>>(H2 + 96*128, lin_w, lin_b, out);
}

// Round 4
// 339.982 us; speedup vs baseline: 1.5971x; 1.1187x over previous
//
#include <hip/hip_runtime.h>
#include <math.h>

#define N_EDGES_C 1048576
#define N_TOTAL_C 65536

typedef _Float16 h2v __attribute__((ext_vector_type(2)));
typedef _Float16 h4v __attribute__((ext_vector_type(4)));

#if defined(__has_builtin)
#if __has_builtin(__builtin_amdgcn_fdot2)
#define HAS_FDOT2 1
#endif
#endif

__device__ __forceinline__ float fdot2(h2v a, h2v b, float c) {
#ifdef HAS_FDOT2
    return __builtin_amdgcn_fdot2(a, b, c, false);
#else
    return c + (float)a.x * (float)b.x + (float)a.y * (float)b.y;
#endif
}

__device__ __forceinline__ float sigf(float x){ return 1.0f/(1.0f+expf(-x)); }
__device__ __forceinline__ float lrelu(float x){ return (x>=0.f)? x : 0.2f*x; }

// ---------------- 1. node transform: xp(fp16) = x @ W_gat, asrc/adst(fp32) ----------------
__global__ void node_transform(const float* __restrict__ x, const float* __restrict__ Wg,
                               const float* __restrict__ a_src, const float* __restrict__ a_dst,
                               _Float16* __restrict__ xph, float* __restrict__ asrc, float* __restrict__ adst)
{
    __shared__ float Ws[12*96];
    __shared__ float as_s[96], ad_s[96];
    int tid = threadIdx.x;
    for (int i = tid; i < 1152; i += 256) Ws[i] = Wg[i];
    if (tid < 96) { as_s[tid] = a_src[tid]; ad_s[tid] = a_dst[tid]; }
    __syncthreads();
    int n = blockIdx.x * 256 + tid;
    const float4* xv = (const float4*)(x + (size_t)n * 12);
    float4 v0 = xv[0], v1 = xv[1], v2 = xv[2];
    float xr[12] = {v0.x,v0.y,v0.z,v0.w, v1.x,v1.y,v1.z,v1.w, v2.x,v2.y,v2.z,v2.w};
    _Float16* xpr = xph + (size_t)n * 96;
    #pragma unroll
    for (int h = 0; h < 8; h++) {
        float xp_[12];
        #pragma unroll
        for (int c = 0; c < 12; c++) {
            float acc = 0.f;
            #pragma unroll
            for (int k = 0; k < 12; k++) acc += xr[k] * Ws[k*96 + h*12 + c];
            xp_[c] = acc;
        }
        h4v* o = (h4v*)(xpr + h*12);      // offset h*24 B: 8-byte aligned
        #pragma unroll
        for (int j = 0; j < 3; j++) {
            h4v t;
            t.x = (_Float16)xp_[j*4+0]; t.y = (_Float16)xp_[j*4+1];
            t.z = (_Float16)xp_[j*4+2]; t.w = (_Float16)xp_[j*4+3];
            o[j] = t;
        }
        float sa = 0.f, sd = 0.f;
        #pragma unroll
        for (int c = 0; c < 12; c++) { sa += xp_[c]*as_s[h*12+c]; sd += xp_[c]*ad_s[h*12+c]; }
        asrc[(size_t)n*8 + h] = sa;
        adst[(size_t)n*8 + h] = sd;
    }
}

// ---------------- 2a. degree count (int4: 4 edges/thread) ----------------
__global__ void deg_count(const int* __restrict__ ei, int* __restrict__ deg)
{
    int i = blockIdx.x * 256 + threadIdx.x;
    int4 d = ((const int4*)(ei + N_EDGES_C))[i];
    atomicAdd(&deg[d.x], 1);
    atomicAdd(&deg[d.y], 1);
    atomicAdd(&deg[d.z], 1);
    atomicAdd(&deg[d.w], 1);
}

// ---------------- 2b. exclusive scan over 65536 degrees (single block, int4 I/O) ----------------
__global__ void scan_build(const int* __restrict__ deg, int* __restrict__ rowptr, int* __restrict__ cursor)
{
    __shared__ int sums[1024];
    int tid = threadIdx.x;
    // thread handles nodes [tid*64, tid*64+64) as 16 int4s
    int4 v[16];
    const int4* deg4 = (const int4*)deg;
    #pragma unroll
    for (int j = 0; j < 16; j++) v[j] = deg4[tid*16 + j];
    int s = 0;
    #pragma unroll
    for (int j = 0; j < 16; j++) s += v[j].x + v[j].y + v[j].z + v[j].w;
    sums[tid] = s;
    __syncthreads();
    for (int off = 1; off < 1024; off <<= 1) {
        int t = 0;
        if (tid >= off) t = sums[tid - off];
        __syncthreads();
        if (tid >= off) sums[tid] += t;
        __syncthreads();
    }
    int run = sums[tid] - s;   // exclusive prefix of this chunk
    int4* rp4 = (int4*)rowptr;
    int4* cu4 = (int4*)cursor;
    #pragma unroll
    for (int j = 0; j < 16; j++) {
        int4 r;
        r.x = run; run += v[j].x;
        r.y = run; run += v[j].y;
        r.z = run; run += v[j].z;
        r.w = run; run += v[j].w;
        rp4[tid*16 + j] = r;
        cu4[tid*16 + j] = r;
    }
    if (tid == 1023) rowptr[65536] = run;
}

// ---------------- 2c. dst-range-binned CSR scatter ----------------
// CSR is dst-ordered, so dst range [g*8192,(g+1)*8192) owns a contiguous ~512KB
// csr slice. Group g = blockIdx&7 (XCD round-robin heuristic) scans ALL edges
// (int4, LLC-absorbed re-reads) but scatters only its own range -> each csr
// line is dirtied by one XCD's L2 and written back once (round-3: 17x write amp).
__global__ void edge_scatter(const int* __restrict__ ei, int* __restrict__ cursor, int* __restrict__ csr)
{
    int g = blockIdx.x & 7;
    int slice = blockIdx.x >> 3;          // 0..63
    const int4* dst4 = (const int4*)(ei + N_EDGES_C);
    const int4* src4 = (const int4*)ei;
    for (int i = threadIdx.x; i < 4096; i += 256) {
        int idx = slice * 4096 + i;
        int4 d = dst4[idx];
        int4 s = src4[idx];
        if ((d.x >> 13) == g) { int p = atomicAdd(&cursor[d.x], 1); csr[p] = s.x; }
        if ((d.y >> 13) == g) { int p = atomicAdd(&cursor[d.y], 1); csr[p] = s.y; }
        if ((d.z >> 13) == g) { int p = atomicAdd(&cursor[d.z], 1); csr[p] = s.z; }
        if ((d.w >> 13) == g) { int p = atomicAdd(&cursor[d.w], 1); csr[p] = s.w; }
    }
}

// ---------------- 3. per-(node,head) online-softmax aggregation + BN + log_softmax ----------------
__global__ void gat_aggregate(const _Float16* __restrict__ xph, const float* __restrict__ asrc,
                              const float* __restrict__ adst,
                              const int* __restrict__ rowptr, const int* __restrict__ csr_src,
                              const float* __restrict__ gat_bias, const float* __restrict__ bn_gamma,
                              const float* __restrict__ bn_beta, const float* __restrict__ bn_mean,
                              const float* __restrict__ bn_var, float* __restrict__ seq)
{
    int gid = blockIdx.x * 256 + threadIdx.x;
    int n = gid >> 3;
    int h = gid & 7;

    float adst_n = adst[(size_t)n*8 + h];
    // self-loop initializes the online softmax state
    float m = lrelu(asrc[(size_t)n*8 + h] + adst_n);
    float d = 1.0f;
    float acc[12];
    {
        const h4v* xv = (const h4v*)(xph + (size_t)n*96 + h*12);
        h4v a0 = xv[0], a1 = xv[1], a2 = xv[2];
        acc[0]=(float)a0.x; acc[1]=(float)a0.y; acc[2]=(float)a0.z; acc[3]=(float)a0.w;
        acc[4]=(float)a1.x; acc[5]=(float)a1.y; acc[6]=(float)a1.z; acc[7]=(float)a1.w;
        acc[8]=(float)a2.x; acc[9]=(float)a2.y; acc[10]=(float)a2.z; acc[11]=(float)a2.w;
    }
    int beg = rowptr[n], end = rowptr[n+1];
    for (int i = beg; i < end; i++) {
        int src = csr_src[i];
        float e = lrelu(asrc[(size_t)src*8 + h] + adst_n);
        float mn = fmaxf(m, e);
        float sc = expf(m - mn);
        float w  = expf(e - mn);
        m = mn;
        d = d * sc + w;
        const h4v* sv = (const h4v*)(xph + (size_t)src*96 + h*12);
        h4v b0 = sv[0], b1 = sv[1], b2 = sv[2];
        acc[0]=acc[0]*sc + w*(float)b0.x; acc[1]=acc[1]*sc + w*(float)b0.y; acc[2]=acc[2]*sc + w*(float)b0.z; acc[3]=acc[3]*sc + w*(float)b0.w;
        acc[4]=acc[4]*sc + w*(float)b1.x; acc[5]=acc[5]*sc + w*(float)b1.y; acc[6]=acc[6]*sc + w*(float)b1.z; acc[7]=acc[7]*sc + w*(float)b1.w;
        acc[8]=acc[8]*sc + w*(float)b2.x; acc[9]=acc[9]*sc + w*(float)b2.y; acc[10]=acc[10]*sc + w*(float)b2.z; acc[11]=acc[11]*sc + w*(float)b2.w;
    }
    float inv = 1.0f / (d + 1e-16f);
    float res[12];
    #pragma unroll
    for (int c = 0; c < 12; c++) {
        float v = acc[c] * inv;
        v += __shfl_xor(v, 1);
        v += __shfl_xor(v, 2);
        v += __shfl_xor(v, 4);
        res[c] = v * 0.125f;     // mean over 8 heads
    }
    if (h == 0) {
        float vals[12];
        float mx = -1e30f;
        #pragma unroll
        for (int c = 0; c < 12; c++) {
            float v = res[c] + gat_bias[c];
            v = (v - bn_mean[c]) * rsqrtf(bn_var[c] + 1e-5f) * bn_gamma[c] + bn_beta[c];
            vals[c] = v;
            mx = fmaxf(mx, v);
        }
        float sum = 0.f;
        #pragma unroll
        for (int c = 0; c < 12; c++) sum += expf(vals[c] - mx);
        float lse = logf(sum) + mx;
        #pragma unroll
        for (int c = 0; c < 12; c++) seq[(size_t)c * N_TOTAL_C + n] = vals[c] - lse;
    }
}

// ---------------- 4. X1 = seq(384x2048) @ w_ih1(128x2048)^T, split-K x16 ----------------
__global__ void gemm_x1(const float* __restrict__ A, const float* __restrict__ B,
                        float* __restrict__ C)
{
    __shared__ float As[32][33], Bs[32][33];
    const int K = 2048, N = 128;
    int tid = threadIdx.x;
    int tx = tid & 31, ty = tid >> 5;
    int bm = blockIdx.x * 32, bn = blockIdx.y * 32;
    int kbase = blockIdx.z * 128;
    float acc[4] = {0.f,0.f,0.f,0.f};
    for (int kk = 0; kk < 128; kk += 32) {
        int k0 = kbase + kk;
        #pragma unroll
        for (int i = 0; i < 4; i++) {
            int r = ty + i*8;
            As[r][tx] = A[(size_t)(bm + r) * K + k0 + tx];
            Bs[r][tx] = B[(size_t)(bn + r) * K + k0 + tx];
        }
        __syncthreads();
        #pragma unroll
        for (int k = 0; k < 32; k++) {
            float bv = Bs[tx][k];
            #pragma unroll
            for (int i = 0; i < 4; i++) acc[i] += As[ty + i*8][k] * bv;
        }
        __syncthreads();
    }
    #pragma unroll
    for (int i = 0; i < 4; i++)
        atomicAdd(&C[(size_t)(bm + ty + i*8) * N + bn + tx], acc[i]);
}

// ---------------- 5. fused LSTM1(2048->32) + LSTM2(32->128) ----------------
__global__ __launch_bounds__(512)
void lstm_fused(const float* __restrict__ X1, const float* __restrict__ w_hh1,
                const float* __restrict__ b_ih1, const float* __restrict__ b_hh1,
                const float* __restrict__ w_ih2, const float* __restrict__ w_hh2,
                const float* __restrict__ b_ih2, const float* __restrict__ b_hh2,
                float* __restrict__ H2)
{
    __shared__ float whh1[128*33];             // padded stride 33
    __shared__ float b1s[128];
    __shared__ float h1[32], c1[32];
    __shared__ __align__(16) _Float16 h1s[32]; // h1 as fp16 for dot2
    __shared__ __align__(16) _Float16 h2s[128];// h2 as fp16 for dot2
    __shared__ float c2[128];
    __shared__ float g1s[128], g2s[512];
    int tid = threadIdx.x;
    int b = blockIdx.x;

    // --- time-invariant weight preload into registers (fp16 pairs) ---
    h2v whh[64];
    {
        const float2* wh = (const float2*)(w_hh2 + (size_t)tid * 128);
        #pragma unroll
        for (int k = 0; k < 64; k++) {
            float2 v = wh[k];
            h2v t; t.x = (_Float16)v.x; t.y = (_Float16)v.y;
            whh[k] = t;
        }
    }
    h2v wih[16];
    {
        const float2* wi = (const float2*)(w_ih2 + (size_t)tid * 32);
        #pragma unroll
        for (int k = 0; k < 16; k++) {
            float2 v = wi[k];
            h2v t; t.x = (_Float16)v.x; t.y = (_Float16)v.y;
            wih[k] = t;
        }
    }
    float b2 = b_ih2[tid] + b_hh2[tid];

    for (int i = tid; i < 128*32; i += 512) whh1[(i >> 5)*33 + (i & 31)] = w_hh1[i];
    if (tid < 128) b1s[tid] = b_ih1[tid] + b_hh1[tid];
    if (tid < 32)  { h1[tid] = 0.f; c1[tid] = 0.f; h1s[tid] = (_Float16)0.f; }
    if (tid < 128) { c2[tid] = 0.f; h2s[tid] = (_Float16)0.f; }
    __syncthreads();

    for (int t = 0; t < 12; t++) {
        // Phase 1: all 512 threads run the hh2 matvec from registers;
        // threads <128 additionally compute the LSTM1 gate.
        float p0 = b2, p1 = 0.f, p2 = 0.f, p3 = 0.f;
        #pragma unroll
        for (int j = 0; j < 16; j++) {
            float4 f = ((const float4*)h2s)[j];   // 8 halfs per ds_read_b128
            p0 = fdot2(__builtin_bit_cast(h2v, f.x), whh[j*4+0], p0);
            p1 = fdot2(__builtin_bit_cast(h2v, f.y), whh[j*4+1], p1);
            p2 = fdot2(__builtin_bit_cast(h2v, f.z), whh[j*4+2], p2);
            p3 = fdot2(__builtin_bit_cast(h2v, f.w), whh[j*4+3], p3);
        }
        float acc2 = (p0 + p1) + (p2 + p3);

        if (tid < 128) {
            const float* wr = &whh1[tid * 33];
            float acc = X1[((size_t)t*32 + b)*128 + tid] + b1s[tid];
            #pragma unroll
            for (int k = 0; k < 32; k++) acc += h1[k] * wr[k];
            g1s[tid] = acc;
        }
        __syncthreads();
        // Phase 2: LSTM1 activation
        if (tid < 32) {
            float ig = sigf(g1s[tid]), fg = sigf(g1s[32+tid]);
            float gg = tanhf(g1s[64+tid]), og = sigf(g1s[96+tid]);
            float cn = fg * c1[tid] + ig * gg;
            c1[tid] = cn;
            float hn = og * tanhf(cn);
            h1[tid] = hn;
            h1s[tid] = (_Float16)hn;
        }
        __syncthreads();
        // Phase 3: finish LSTM2 gate with ih2 contribution (h1 now fresh)
        {
            float q0 = 0.f, q1 = 0.f, q2 = 0.f, q3 = 0.f;
            #pragma unroll
            for (int j = 0; j < 4; j++) {
                float4 f = ((const float4*)h1s)[j];
                q0 = fdot2(__builtin_bit_cast(h2v, f.x), wih[j*4+0], q0);
                q1 = fdot2(__builtin_bit_cast(h2v, f.y), wih[j*4+1], q1);
                q2 = fdot2(__builtin_bit_cast(h2v, f.z), wih[j*4+2], q2);
                q3 = fdot2(__builtin_bit_cast(h2v, f.w), wih[j*4+3], q3);
            }
            g2s[tid] = acc2 + (q0 + q1) + (q2 + q3);
        }
        __syncthreads();
        // Phase 4: LSTM2 activation + publish h2
        if (tid < 128) {
            float ig = sigf(g2s[tid]), fg = sigf(g2s[128+tid]);
            float gg = tanhf(g2s[256+tid]), og = sigf(g2s[384+tid]);
            float cn = fg * c2[tid] + ig * gg;
            c2[tid] = cn;
            float hn = og * tanhf(cn);
            h2s[tid] = (_Float16)hn;
            if (t >= 3) H2[((size_t)t*32 + b)*128 + tid] = hn;
        }
        __syncthreads();
    }
}

// ---------------- 6. out = H2[3:] (288x128) @ lin_w(2048x128)^T + lin_b ----------------
__global__ void gemm_out(const float* __restrict__ A, const float* __restrict__ B,
                         const float* __restrict__ bias, float* __restrict__ out)
{
    __shared__ float As[32][33], Bs[32][33];
    const int K = 128;
    int tid = threadIdx.x;
    int tx = tid & 31, ty = tid >> 5;
    int bm = blockIdx.x * 32, bn = blockIdx.y * 32;
    float acc[4] = {0.f,0.f,0.f,0.f};
    for (int k0 = 0; k0 < K; k0 += 32) {
        #pragma unroll
        for (int i = 0; i < 4; i++) {
            int r = ty + i*8;
            As[r][tx] = A[(size_t)(bm + r) * K + k0 + tx];
            Bs[r][tx] = B[(size_t)(bn + r) * K + k0 + tx];
        }
        __syncthreads();
        #pragma unroll
        for (int kk = 0; kk < 32; kk++) {
            float bv = Bs[tx][kk];
            #pragma unroll
            for (int i = 0; i < 4; i++) acc[i] += As[ty + i*8][kk] * bv;
        }
        __syncthreads();
    }
    int j = blockIdx.x;            // time slot within last 9 (rows are m = j*32 + b)
    int nn = bn + tx;
    float bv = bias[nn];
    #pragma unroll
    for (int i = 0; i < 4; i++) {
        int bb = ty + i*8;
        out[((size_t)bb * 2048 + nn) * 9 + j] = acc[i] + bv;
    }
}

extern "C" void kernel_launch(void* const* d_in, const int* in_sizes, int n_in,
                              void* d_out, int out_size, void* d_ws, size_t ws_size,
                              hipStream_t stream)
{
    const float* x        = (const float*)d_in[0];
    const int*   ei       = (const int*)  d_in[1];
    const float* W_gat    = (const float*)d_in[2];
    const float* a_src    = (const float*)d_in[3];
    const float* a_dst    = (const float*)d_in[4];
    const float* gat_bias = (const float*)d_in[5];
    const float* bn_gamma = (const float*)d_in[6];
    const float* bn_beta  = (const float*)d_in[7];
    const float* bn_mean  = (const float*)d_in[8];
    const float* bn_var   = (const float*)d_in[9];
    const float* w_ih1    = (const float*)d_in[10];
    const float* w_hh1    = (const float*)d_in[11];
    const float* b_ih1    = (const float*)d_in[12];
    const float* b_hh1    = (const float*)d_in[13];
    const float* w_ih2    = (const float*)d_in[14];
    const float* w_hh2    = (const float*)d_in[15];
    const float* b_ih2    = (const float*)d_in[16];
    const float* b_hh2    = (const float*)d_in[17];
    const float* lin_w    = (const float*)d_in[18];
    const float* lin_b    = (const float*)d_in[19];
    float* out = (float*)d_out;

    float* ws = (float*)d_ws;
    _Float16* xph = (_Float16*)ws;          // 6291456 halfs = 3145728 float slots
    float* asrc = ws   + 3145728;           // 524288
    float* adst = asrc + 524288;            // 524288
    float* seq  = adst + 524288;            // 12*65536 = 786432
    float* X1   = seq  + 786432;            // 384*128  = 49152
    float* H2   = X1   + 49152;             // 384*128  = 49152
    int* rowptr = (int*)(H2 + 49152);       // 65537 (reserve 65540 for 16B align)
    int* cursor = rowptr + 65540;           // 65536
    int* deg    = cursor + 65536;           // 65536
    int* csr    = deg    + 65536;           // 1048576
    // total ~25.3 MB of d_ws

    hipMemsetAsync(deg, 0, 65536 * sizeof(int), stream);
    hipMemsetAsync(X1, 0, 49152 * sizeof(float), stream);
    node_transform<<<256, 256, 0, stream>>>(x, W_gat, a_src, a_dst, xph, asrc, adst);
    deg_count   <<<1024, 256, 0, stream>>>(ei, deg);
    scan_build  <<<1, 1024, 0, stream>>>(deg, rowptr, cursor);
    edge_scatter<<<512, 256, 0, stream>>>(ei, cursor, csr);
    gat_aggregate<<<2048, 256, 0, stream>>>(xph, asrc, adst, rowptr, csr,
                                            gat_bias, bn_gamma, bn_beta, bn_mean, bn_var, seq);
    gemm_x1<<<dim3(12, 4, 16), 256, 0, stream>>>(seq, w_ih1, X1);
    lstm_fused<<<32, 512, 0, stream>>>(X1, w_hh1, b_ih1, b_hh1, w_ih2, w_hh2, b_ih2, b_hh2, H2);
    gemm_out<<<dim3(9, 64), 256, 0, stream>>>(H2 + 96*128, lin_w, lin_b, out);
}

// Round 5
// 330.786 us; speedup vs baseline: 1.6415x; 1.0278x over previous
//
#include <hip/hip_runtime.h>
#include <math.h>

#define N_EDGES_C 1048576
#define N_TOTAL_C 65536

typedef _Float16 h2v __attribute__((ext_vector_type(2)));
typedef _Float16 h4v __attribute__((ext_vector_type(4)));

#if defined(__has_builtin)
#if __has_builtin(__builtin_amdgcn_fdot2)
#define HAS_FDOT2 1
#endif
#endif

__device__ __forceinline__ float fdot2(h2v a, h2v b, float c) {
#ifdef HAS_FDOT2
    return __builtin_amdgcn_fdot2(a, b, c, false);
#else
    return c + (float)a.x * (float)b.x + (float)a.y * (float)b.y;
#endif
}

__device__ __forceinline__ float sigf(float x){ return 1.0f/(1.0f+expf(-x)); }
__device__ __forceinline__ float lrelu(float x){ return (x>=0.f)? x : 0.2f*x; }

// xpp row layout: 128 halfs (256 B) per node = 8 head slots x 16 halfs:
//   [ch0..ch11 fp16 | asrc_h fp32 (halfs 12-13) | adst_h fp32 (halfs 14-15)]
// One edge gather = 2 x dwordx4 per lane, both hitting the same 4 cache lines.

// ---------------- 1. fused: node transform (blocks 0..255) + degree count (blocks 256..1279) ----------------
__global__ void prep_kernel(const float* __restrict__ x, const float* __restrict__ Wg,
                            const float* __restrict__ a_src, const float* __restrict__ a_dst,
                            _Float16* __restrict__ xpp,
                            const int* __restrict__ ei, int* __restrict__ deg)
{
    int tid = threadIdx.x;
    if (blockIdx.x >= 256) {        // --- degree count: 4 edges/thread ---
        int i = (blockIdx.x - 256) * 256 + tid;
        int4 d = ((const int4*)(ei + N_EDGES_C))[i];
        atomicAdd(&deg[d.x], 1);
        atomicAdd(&deg[d.y], 1);
        atomicAdd(&deg[d.z], 1);
        atomicAdd(&deg[d.w], 1);
        return;
    }
    __shared__ float Ws[12*96];
    __shared__ float as_s[96], ad_s[96];
    for (int i = tid; i < 1152; i += 256) Ws[i] = Wg[i];
    if (tid < 96) { as_s[tid] = a_src[tid]; ad_s[tid] = a_dst[tid]; }
    __syncthreads();
    int n = blockIdx.x * 256 + tid;
    const float4* xv = (const float4*)(x + (size_t)n * 12);
    float4 v0 = xv[0], v1 = xv[1], v2 = xv[2];
    float xr[12] = {v0.x,v0.y,v0.z,v0.w, v1.x,v1.y,v1.z,v1.w, v2.x,v2.y,v2.z,v2.w};
    float4* orow = (float4*)(xpp + (size_t)n * 128);
    #pragma unroll
    for (int h = 0; h < 8; h++) {
        float xp_[12];
        #pragma unroll
        for (int c = 0; c < 12; c++) {
            float acc = 0.f;
            #pragma unroll
            for (int k = 0; k < 12; k++) acc += xr[k] * Ws[k*96 + h*12 + c];
            xp_[c] = acc;
        }
        float sa = 0.f, sd = 0.f;
        #pragma unroll
        for (int c = 0; c < 12; c++) { sa += xp_[c]*as_s[h*12+c]; sd += xp_[c]*ad_s[h*12+c]; }
        union { _Float16 hh[16]; float ff[8]; float4 f4[2]; } s;
        #pragma unroll
        for (int c = 0; c < 12; c++) s.hh[c] = (_Float16)xp_[c];
        s.ff[6] = sa;            // halfs 12-13
        s.ff[7] = sd;            // halfs 14-15
        orow[h*2+0] = s.f4[0];
        orow[h*2+1] = s.f4[1];
    }
}

// ---------------- 2b. exclusive scan over 65536 degrees (single block, int4 I/O) ----------------
__global__ void scan_build(const int* __restrict__ deg, int* __restrict__ rowptr, int* __restrict__ cursor)
{
    __shared__ int sums[1024];
    int tid = threadIdx.x;
    int4 v[16];
    const int4* deg4 = (const int4*)deg;
    #pragma unroll
    for (int j = 0; j < 16; j++) v[j] = deg4[tid*16 + j];
    int s = 0;
    #pragma unroll
    for (int j = 0; j < 16; j++) s += v[j].x + v[j].y + v[j].z + v[j].w;
    sums[tid] = s;
    __syncthreads();
    for (int off = 1; off < 1024; off <<= 1) {
        int t = 0;
        if (tid >= off) t = sums[tid - off];
        __syncthreads();
        if (tid >= off) sums[tid] += t;
        __syncthreads();
    }
    int run = sums[tid] - s;   // exclusive prefix of this chunk
    int4* rp4 = (int4*)rowptr;
    int4* cu4 = (int4*)cursor;
    #pragma unroll
    for (int j = 0; j < 16; j++) {
        int4 r;
        r.x = run; run += v[j].x;
        r.y = run; run += v[j].y;
        r.z = run; run += v[j].z;
        r.w = run; run += v[j].w;
        rp4[tid*16 + j] = r;
        cu4[tid*16 + j] = r;
    }
    if (tid == 1023) rowptr[65536] = run;
}

// ---------------- 2c. dst-range-binned CSR scatter ----------------
__global__ void edge_scatter(const int* __restrict__ ei, int* __restrict__ cursor, int* __restrict__ csr)
{
    int g = blockIdx.x & 7;
    int slice = blockIdx.x >> 3;          // 0..63
    const int4* dst4 = (const int4*)(ei + N_EDGES_C);
    const int4* src4 = (const int4*)ei;
    for (int i = threadIdx.x; i < 4096; i += 256) {
        int idx = slice * 4096 + i;
        int4 d = dst4[idx];
        int4 s = src4[idx];
        if ((d.x >> 13) == g) { int p = atomicAdd(&cursor[d.x], 1); csr[p] = s.x; }
        if ((d.y >> 13) == g) { int p = atomicAdd(&cursor[d.y], 1); csr[p] = s.y; }
        if ((d.z >> 13) == g) { int p = atomicAdd(&cursor[d.z], 1); csr[p] = s.z; }
        if ((d.w >> 13) == g) { int p = atomicAdd(&cursor[d.w], 1); csr[p] = s.w; }
    }
}

// ---------------- 3. per-(node,head) softmax aggregation + BN + log_softmax ----------------
// No max-shift: logits bounded (~|7|), exp(e) safe in fp32, alpha identical.
__global__ void gat_aggregate(const _Float16* __restrict__ xpp,
                              const int* __restrict__ rowptr, const int* __restrict__ csr_src,
                              const float* __restrict__ gat_bias, const float* __restrict__ bn_gamma,
                              const float* __restrict__ bn_beta, const float* __restrict__ bn_mean,
                              const float* __restrict__ bn_var, float* __restrict__ seq)
{
    int gid = blockIdx.x * 256 + threadIdx.x;
    int n = gid >> 3;
    int h = gid & 7;

    float acc[12];
    float adst_n, d;
    {
        const float4* p = (const float4*)(xpp + (size_t)n*128 + h*16);
        float4 f0 = p[0], f1 = p[1];
        float asrc_n = f1.z;
        adst_n = f1.w;
        float w = __expf(lrelu(asrc_n + adst_n));   // self-loop term
        d = w;
        h2v c0 = __builtin_bit_cast(h2v, f0.x), c1 = __builtin_bit_cast(h2v, f0.y);
        h2v c2 = __builtin_bit_cast(h2v, f0.z), c3 = __builtin_bit_cast(h2v, f0.w);
        h2v c4 = __builtin_bit_cast(h2v, f1.x), c5 = __builtin_bit_cast(h2v, f1.y);
        acc[0]=w*(float)c0.x; acc[1]=w*(float)c0.y; acc[2]=w*(float)c1.x; acc[3]=w*(float)c1.y;
        acc[4]=w*(float)c2.x; acc[5]=w*(float)c2.y; acc[6]=w*(float)c3.x; acc[7]=w*(float)c3.y;
        acc[8]=w*(float)c4.x; acc[9]=w*(float)c4.y; acc[10]=w*(float)c5.x; acc[11]=w*(float)c5.y;
    }
    int beg = rowptr[n], end = rowptr[n+1];
    for (int i = beg; i < end; i++) {
        int src = csr_src[i];
        const float4* p = (const float4*)(xpp + (size_t)src*128 + h*16);
        float4 f0 = p[0], f1 = p[1];
        float w = __expf(lrelu(f1.z + adst_n));
        d += w;
        h2v c0 = __builtin_bit_cast(h2v, f0.x), c1 = __builtin_bit_cast(h2v, f0.y);
        h2v c2 = __builtin_bit_cast(h2v, f0.z), c3 = __builtin_bit_cast(h2v, f0.w);
        h2v c4 = __builtin_bit_cast(h2v, f1.x), c5 = __builtin_bit_cast(h2v, f1.y);
        acc[0]+=w*(float)c0.x; acc[1]+=w*(float)c0.y; acc[2]+=w*(float)c1.x; acc[3]+=w*(float)c1.y;
        acc[4]+=w*(float)c2.x; acc[5]+=w*(float)c2.y; acc[6]+=w*(float)c3.x; acc[7]+=w*(float)c3.y;
        acc[8]+=w*(float)c4.x; acc[9]+=w*(float)c4.y; acc[10]+=w*(float)c5.x; acc[11]+=w*(float)c5.y;
    }
    float inv = 1.0f / (d + 1e-16f);
    float res[12];
    #pragma unroll
    for (int c = 0; c < 12; c++) {
        float v = acc[c] * inv;
        v += __shfl_xor(v, 1);
        v += __shfl_xor(v, 2);
        v += __shfl_xor(v, 4);
        res[c] = v * 0.125f;     // mean over 8 heads
    }
    if (h == 0) {
        float vals[12];
        float mx = -1e30f;
        #pragma unroll
        for (int c = 0; c < 12; c++) {
            float v = res[c] + gat_bias[c];
            v = (v - bn_mean[c]) * rsqrtf(bn_var[c] + 1e-5f) * bn_gamma[c] + bn_beta[c];
            vals[c] = v;
            mx = fmaxf(mx, v);
        }
        float sum = 0.f;
        #pragma unroll
        for (int c = 0; c < 12; c++) sum += __expf(vals[c] - mx);
        float lse = __logf(sum) + mx;
        #pragma unroll
        for (int c = 0; c < 12; c++) seq[(size_t)c * N_TOTAL_C + n] = vals[c] - lse;
    }
}

// ---------------- 4. X1 = seq(384x2048) @ w_ih1(128x2048)^T, split-K x16 ----------------
__global__ void gemm_x1(const float* __restrict__ A, const float* __restrict__ B,
                        float* __restrict__ C)
{
    __shared__ float As[32][33], Bs[32][33];
    const int K = 2048, N = 128;
    int tid = threadIdx.x;
    int tx = tid & 31, ty = tid >> 5;
    int bm = blockIdx.x * 32, bn = blockIdx.y * 32;
    int kbase = blockIdx.z * 128;
    float acc[4] = {0.f,0.f,0.f,0.f};
    for (int kk = 0; kk < 128; kk += 32) {
        int k0 = kbase + kk;
        #pragma unroll
        for (int i = 0; i < 4; i++) {
            int r = ty + i*8;
            As[r][tx] = A[(size_t)(bm + r) * K + k0 + tx];
            Bs[r][tx] = B[(size_t)(bn + r) * K + k0 + tx];
        }
        __syncthreads();
        #pragma unroll
        for (int k = 0; k < 32; k++) {
            float bv = Bs[tx][k];
            #pragma unroll
            for (int i = 0; i < 4; i++) acc[i] += As[ty + i*8][k] * bv;
        }
        __syncthreads();
    }
    #pragma unroll
    for (int i = 0; i < 4; i++)
        atomicAdd(&C[(size_t)(bm + ty + i*8) * N + bn + tx], acc[i]);
}

// ---------------- 5. fused LSTM1(2048->32) + LSTM2(32->128) ----------------
__global__ __launch_bounds__(512)
void lstm_fused(const float* __restrict__ X1, const float* __restrict__ w_hh1,
                const float* __restrict__ b_ih1, const float* __restrict__ b_hh1,
                const float* __restrict__ w_ih2, const float* __restrict__ w_hh2,
                const float* __restrict__ b_ih2, const float* __restrict__ b_hh2,
                float* __restrict__ H2)
{
    __shared__ float whh1[128*33];             // padded stride 33
    __shared__ float b1s[128];
    __shared__ float h1[32], c1[32];
    __shared__ __align__(16) _Float16 h1s[32]; // h1 as fp16 for dot2
    __shared__ __align__(16) _Float16 h2s[128];// h2 as fp16 for dot2
    __shared__ float c2[128];
    __shared__ float g1s[128], g2s[512];
    int tid = threadIdx.x;
    int b = blockIdx.x;

    // --- time-invariant weight preload into registers (fp16 pairs) ---
    h2v whh[64];
    {
        const float2* wh = (const float2*)(w_hh2 + (size_t)tid * 128);
        #pragma unroll
        for (int k = 0; k < 64; k++) {
            float2 v = wh[k];
            h2v t; t.x = (_Float16)v.x; t.y = (_Float16)v.y;
            whh[k] = t;
        }
    }
    h2v wih[16];
    {
        const float2* wi = (const float2*)(w_ih2 + (size_t)tid * 32);
        #pragma unroll
        for (int k = 0; k < 16; k++) {
            float2 v = wi[k];
            h2v t; t.x = (_Float16)v.x; t.y = (_Float16)v.y;
            wih[k] = t;
        }
    }
    float b2 = b_ih2[tid] + b_hh2[tid];

    for (int i = tid; i < 128*32; i += 512) whh1[(i >> 5)*33 + (i & 31)] = w_hh1[i];
    if (tid < 128) b1s[tid] = b_ih1[tid] + b_hh1[tid];
    if (tid < 32)  { h1[tid] = 0.f; c1[tid] = 0.f; h1s[tid] = (_Float16)0.f; }
    if (tid < 128) { c2[tid] = 0.f; h2s[tid] = (_Float16)0.f; }
    __syncthreads();

    for (int t = 0; t < 12; t++) {
        // Phase 1: all 512 threads run the hh2 matvec from registers;
        // threads <128 additionally compute the LSTM1 gate.
        float p0 = b2, p1 = 0.f, p2 = 0.f, p3 = 0.f;
        #pragma unroll
        for (int j = 0; j < 16; j++) {
            float4 f = ((const float4*)h2s)[j];   // 8 halfs per ds_read_b128
            p0 = fdot2(__builtin_bit_cast(h2v, f.x), whh[j*4+0], p0);
            p1 = fdot2(__builtin_bit_cast(h2v, f.y), whh[j*4+1], p1);
            p2 = fdot2(__builtin_bit_cast(h2v, f.z), whh[j*4+2], p2);
            p3 = fdot2(__builtin_bit_cast(h2v, f.w), whh[j*4+3], p3);
        }
        float acc2 = (p0 + p1) + (p2 + p3);

        if (tid < 128) {
            const float* wr = &whh1[tid * 33];
            float acc = X1[((size_t)t*32 + b)*128 + tid] + b1s[tid];
            #pragma unroll
            for (int k = 0; k < 32; k++) acc += h1[k] * wr[k];
            g1s[tid] = acc;
        }
        __syncthreads();
        // Phase 2: LSTM1 activation
        if (tid < 32) {
            float ig = sigf(g1s[tid]), fg = sigf(g1s[32+tid]);
            float gg = tanhf(g1s[64+tid]), og = sigf(g1s[96+tid]);
            float cn = fg * c1[tid] + ig * gg;
            c1[tid] = cn;
            float hn = og * tanhf(cn);
            h1[tid] = hn;
            h1s[tid] = (_Float16)hn;
        }
        __syncthreads();
        // Phase 3: finish LSTM2 gate with ih2 contribution (h1 now fresh)
        {
            float q0 = 0.f, q1 = 0.f, q2 = 0.f, q3 = 0.f;
            #pragma unroll
            for (int j = 0; j < 4; j++) {
                float4 f = ((const float4*)h1s)[j];
                q0 = fdot2(__builtin_bit_cast(h2v, f.x), wih[j*4+0], q0);
                q1 = fdot2(__builtin_bit_cast(h2v, f.y), wih[j*4+1], q1);
                q2 = fdot2(__builtin_bit_cast(h2v, f.z), wih[j*4+2], q2);
                q3 = fdot2(__builtin_bit_cast(h2v, f.w), wih[j*4+3], q3);
            }
            g2s[tid] = acc2 + (q0 + q1) + (q2 + q3);
        }
        __syncthreads();
        // Phase 4: LSTM2 activation + publish h2
        if (tid < 128) {
            float ig = sigf(g2s[tid]), fg = sigf(g2s[128+tid]);
            float gg = tanhf(g2s[256+tid]), og = sigf(g2s[384+tid]);
            float cn = fg * c2[tid] + ig * gg;
            c2[tid] = cn;
            float hn = og * tanhf(cn);
            h2s[tid] = (_Float16)hn;
            if (t >= 3) H2[((size_t)t*32 + b)*128 + tid] = hn;
        }
        __syncthreads();
    }
}

// ---------------- 6. out = H2[3:] (288x128) @ lin_w(2048x128)^T + lin_b ----------------
__global__ void gemm_out(const float* __restrict__ A, const float* __restrict__ B,
                         const float* __restrict__ bias, float* __restrict__ out)
{
    __shared__ float As[32][33], Bs[32][33];
    const int K = 128;
    int tid = threadIdx.x;
    int tx = tid & 31, ty = tid >> 5;
    int bm = blockIdx.x * 32, bn = blockIdx.y * 32;
    float acc[4] = {0.f,0.f,0.f,0.f};
    for (int k0 = 0; k0 < K; k0 += 32) {
        #pragma unroll
        for (int i = 0; i < 4; i++) {
            int r = ty + i*8;
            As[r][tx] = A[(size_t)(bm + r) * K + k0 + tx];
            Bs[r][tx] = B[(size_t)(bn + r) * K + k0 + tx];
        }
        __syncthreads();
        #pragma unroll
        for (int kk = 0; kk < 32; kk++) {
            float bv = Bs[tx][kk];
            #pragma unroll
            for (int i = 0; i < 4; i++) acc[i] += As[ty + i*8][kk] * bv;
        }
        __syncthreads();
    }
    int j = blockIdx.x;            // time slot within last 9 (rows are m = j*32 + b)
    int nn = bn + tx;
    float bv = bias[nn];
    #pragma unroll
    for (int i = 0; i < 4; i++) {
        int bb = ty + i*8;
        out[((size_t)bb * 2048 + nn) * 9 + j] = acc[i] + bv;
    }
}

extern "C" void kernel_launch(void* const* d_in, const int* in_sizes, int n_in,
                              void* d_out, int out_size, void* d_ws, size_t ws_size,
                              hipStream_t stream)
{
    const float* x        = (const float*)d_in[0];
    const int*   ei       = (const int*)  d_in[1];
    const float* W_gat    = (const float*)d_in[2];
    const float* a_src    = (const float*)d_in[3];
    const float* a_dst    = (const float*)d_in[4];
    const float* gat_bias = (const float*)d_in[5];
    const float* bn_gamma = (const float*)d_in[6];
    const float* bn_beta  = (const float*)d_in[7];
    const float* bn_mean  = (const float*)d_in[8];
    const float* bn_var   = (const float*)d_in[9];
    const float* w_ih1    = (const float*)d_in[10];
    const float* w_hh1    = (const float*)d_in[11];
    const float* b_ih1    = (const float*)d_in[12];
    const float* b_hh1    = (const float*)d_in[13];
    const float* w_ih2    = (const float*)d_in[14];
    const float* w_hh2    = (const float*)d_in[15];
    const float* b_ih2    = (const float*)d_in[16];
    const float* b_hh2    = (const float*)d_in[17];
    const float* lin_w    = (const float*)d_in[18];
    const float* lin_b    = (const float*)d_in[19];
    float* out = (float*)d_out;

    float* ws = (float*)d_ws;
    _Float16* xpp = (_Float16*)ws;          // 65536*128 halfs = 4194304 float slots (16 MB)
    float* seq  = ws   + 4194304;           // 12*65536 = 786432
    float* X1   = seq  + 786432;            // 384*128  = 49152
    float* H2   = X1   + 49152;             // 384*128  = 49152
    int* rowptr = (int*)(H2 + 49152);       // 65537 (reserve 65540 for 16B align)
    int* cursor = rowptr + 65540;           // 65536
    int* deg    = cursor + 65536;           // 65536
    int* csr    = deg    + 65536;           // 1048576
    // total ~24.6 MB of d_ws

    hipMemsetAsync(deg, 0, 65536 * sizeof(int), stream);
    hipMemsetAsync(X1, 0, 49152 * sizeof(float), stream);
    prep_kernel <<<1280, 256, 0, stream>>>(x, W_gat, a_src, a_dst, xpp, ei, deg);
    scan_build  <<<1, 1024, 0, stream>>>(deg, rowptr, cursor);
    edge_scatter<<<512, 256, 0, stream>>>(ei, cursor, csr);
    gat_aggregate<<<2048, 256, 0, stream>>>(xpp, rowptr, csr,
                                            gat_bias, bn_gamma, bn_beta, bn_mean, bn_var, seq);
    gemm_x1<<<dim3(12, 4, 16), 256, 0, stream>>>(seq, w_ih1, X1);
    lstm_fused<<<32, 512, 0, stream>>>(X1, w_hh1, b_ih1, b_hh1, w_ih2, w_hh2, b_ih2, b_hh2, H2);
    gemm_out<<<dim3(9, 64), 256, 0, stream>>>(H2 + 96*128, lin_w, lin_b, out);
}

// Round 7
// 326.027 us; speedup vs baseline: 1.6655x; 1.0146x over previous
//
#include <hip/hip_runtime.h>
#include <math.h>

#define N_EDGES_C 1048576
#define N_TOTAL_C 65536

typedef _Float16 h2v __attribute__((ext_vector_type(2)));
typedef _Float16 h4v __attribute__((ext_vector_type(4)));
typedef int i4v __attribute__((ext_vector_type(4)));   // native vec4: valid for nontemporal builtins

#if defined(__has_builtin)
#if __has_builtin(__builtin_amdgcn_fdot2)
#define HAS_FDOT2 1
#endif
#endif

__device__ __forceinline__ float fdot2(h2v a, h2v b, float c) {
#ifdef HAS_FDOT2
    return __builtin_amdgcn_fdot2(a, b, c, false);
#else
    return c + (float)a.x * (float)b.x + (float)a.y * (float)b.y;
#endif
}

__device__ __forceinline__ float sigf(float x){ return 1.0f/(1.0f+expf(-x)); }
__device__ __forceinline__ float lrelu(float x){ return (x>=0.f)? x : 0.2f*x; }

// xpp row layout: 128 halfs (256 B) per node = 8 head slots x 16 halfs:
//   [ch0..ch11 fp16 | asrc_h fp32 (halfs 12-13) | adst_h fp32 (halfs 14-15)]

// ---------------- 1. fused prep: node transform (blocks 0..2047, 8 thr/node)
//                   + degree count (blocks 2048..3071) ----------------
// 8 threads per node -> store address = gid*32: wave stores are 2KB contiguous
// (round-5: 1 thr/node gave stride-256 partial lines, 105MB written for 16MB).
__global__ void prep_kernel(const float* __restrict__ x, const float* __restrict__ Wg,
                            const float* __restrict__ a_src, const float* __restrict__ a_dst,
                            _Float16* __restrict__ xpp,
                            const int* __restrict__ ei, int* __restrict__ deg)
{
    int tid = threadIdx.x;
    if (blockIdx.x >= 2048) {        // --- degree count: 4 edges/thread ---
        int i = (blockIdx.x - 2048) * 256 + tid;
        i4v d = __builtin_nontemporal_load((const i4v*)(ei + N_EDGES_C) + i);
        atomicAdd(&deg[d.x], 1);
        atomicAdd(&deg[d.y], 1);
        atomicAdd(&deg[d.z], 1);
        atomicAdd(&deg[d.w], 1);
        return;
    }
    __shared__ float Ws[12*96];
    __shared__ float as_s[96], ad_s[96];
    for (int i = tid; i < 1152; i += 256) Ws[i] = Wg[i];
    if (tid < 96) { as_s[tid] = a_src[tid]; ad_s[tid] = a_dst[tid]; }
    __syncthreads();
    int gid = blockIdx.x * 256 + tid;
    int n = gid >> 3;
    int h = gid & 7;
    const float4* xv = (const float4*)(x + (size_t)n * 12);   // 8 lanes share -> L1 broadcast
    float4 v0 = xv[0], v1 = xv[1], v2 = xv[2];
    float xr[12] = {v0.x,v0.y,v0.z,v0.w, v1.x,v1.y,v1.z,v1.w, v2.x,v2.y,v2.z,v2.w};
    float xp_[12];
    #pragma unroll
    for (int c = 0; c < 12; c++) {
        float acc = 0.f;
        #pragma unroll
        for (int k = 0; k < 12; k++) acc += xr[k] * Ws[k*96 + h*12 + c];
        xp_[c] = acc;
    }
    float sa = 0.f, sd = 0.f;
    #pragma unroll
    for (int c = 0; c < 12; c++) { sa += xp_[c]*as_s[h*12+c]; sd += xp_[c]*ad_s[h*12+c]; }
    union { _Float16 hh[16]; float ff[8]; float4 f4[2]; } s;
    #pragma unroll
    for (int c = 0; c < 12; c++) s.hh[c] = (_Float16)xp_[c];
    s.ff[6] = sa;            // halfs 12-13
    s.ff[7] = sd;            // halfs 14-15
    float4* o = (float4*)(xpp + (size_t)gid * 16);   // byte addr gid*32: coalesced
    o[0] = s.f4[0];
    o[1] = s.f4[1];
}

// ---------------- 2b. exclusive scan over 65536 degrees (single block, int4 I/O) ----------------
__global__ void scan_build(const int* __restrict__ deg, int* __restrict__ rowptr, int* __restrict__ cursor)
{
    __shared__ int sums[1024];
    int tid = threadIdx.x;
    int4 v[16];
    const int4* deg4 = (const int4*)deg;
    #pragma unroll
    for (int j = 0; j < 16; j++) v[j] = deg4[tid*16 + j];
    int s = 0;
    #pragma unroll
    for (int j = 0; j < 16; j++) s += v[j].x + v[j].y + v[j].z + v[j].w;
    sums[tid] = s;
    __syncthreads();
    for (int off = 1; off < 1024; off <<= 1) {
        int t = 0;
        if (tid >= off) t = sums[tid - off];
        __syncthreads();
        if (tid >= off) sums[tid] += t;
        __syncthreads();
    }
    int run = sums[tid] - s;   // exclusive prefix of this chunk
    int4* rp4 = (int4*)rowptr;
    int4* cu4 = (int4*)cursor;
    #pragma unroll
    for (int j = 0; j < 16; j++) {
        int4 r;
        r.x = run; run += v[j].x;
        r.y = run; run += v[j].y;
        r.z = run; run += v[j].z;
        r.w = run; run += v[j].w;
        rp4[tid*16 + j] = r;
        cu4[tid*16 + j] = r;
    }
    if (tid == 1023) rowptr[65536] = run;
}

// ---------------- 2c. dst-range-binned CSR scatter ----------------
// Non-temporal edge loads: the 8MB stream must not evict group-g's dirty csr
// lines from its 4MB XCD L2 before they fill (round-5: 42MB written for 4.2MB).
__global__ void edge_scatter(const int* __restrict__ ei, int* __restrict__ cursor, int* __restrict__ csr)
{
    int g = blockIdx.x & 7;
    int slice = blockIdx.x >> 3;          // 0..63
    const i4v* dst4 = (const i4v*)(ei + N_EDGES_C);
    const i4v* src4 = (const i4v*)ei;
    for (int i = threadIdx.x; i < 4096; i += 256) {
        int idx = slice * 4096 + i;
        i4v d = __builtin_nontemporal_load(&dst4[idx]);
        i4v s = __builtin_nontemporal_load(&src4[idx]);
        if ((d.x >> 13) == g) { int p = atomicAdd(&cursor[d.x], 1); csr[p] = s.x; }
        if ((d.y >> 13) == g) { int p = atomicAdd(&cursor[d.y], 1); csr[p] = s.y; }
        if ((d.z >> 13) == g) { int p = atomicAdd(&cursor[d.z], 1); csr[p] = s.z; }
        if ((d.w >> 13) == g) { int p = atomicAdd(&cursor[d.w], 1); csr[p] = s.w; }
    }
}

// ---------------- 3. per-(node,head) softmax aggregation + BN + log_softmax ----------------
__global__ void gat_aggregate(const _Float16* __restrict__ xpp,
                              const int* __restrict__ rowptr, const int* __restrict__ csr_src,
                              const float* __restrict__ gat_bias, const float* __restrict__ bn_gamma,
                              const float* __restrict__ bn_beta, const float* __restrict__ bn_mean,
                              const float* __restrict__ bn_var, float* __restrict__ seq)
{
    int gid = blockIdx.x * 256 + threadIdx.x;
    int n = gid >> 3;
    int h = gid & 7;

    float acc[12];
    float adst_n, d;
    {
        const float4* p = (const float4*)(xpp + (size_t)n*128 + h*16);
        float4 f0 = p[0], f1 = p[1];
        float asrc_n = f1.z;
        adst_n = f1.w;
        float w = __expf(lrelu(asrc_n + adst_n));   // self-loop term
        d = w;
        h2v c0 = __builtin_bit_cast(h2v, f0.x), c1 = __builtin_bit_cast(h2v, f0.y);
        h2v c2 = __builtin_bit_cast(h2v, f0.z), c3 = __builtin_bit_cast(h2v, f0.w);
        h2v c4 = __builtin_bit_cast(h2v, f1.x), c5 = __builtin_bit_cast(h2v, f1.y);
        acc[0]=w*(float)c0.x; acc[1]=w*(float)c0.y; acc[2]=w*(float)c1.x; acc[3]=w*(float)c1.y;
        acc[4]=w*(float)c2.x; acc[5]=w*(float)c2.y; acc[6]=w*(float)c3.x; acc[7]=w*(float)c3.y;
        acc[8]=w*(float)c4.x; acc[9]=w*(float)c4.y; acc[10]=w*(float)c5.x; acc[11]=w*(float)c5.y;
    }
    int beg = rowptr[n], end = rowptr[n+1];
    for (int i = beg; i < end; i++) {
        int src = csr_src[i];
        const float4* p = (const float4*)(xpp + (size_t)src*128 + h*16);
        float4 f0 = p[0], f1 = p[1];
        float w = __expf(lrelu(f1.z + adst_n));
        d += w;
        h2v c0 = __builtin_bit_cast(h2v, f0.x), c1 = __builtin_bit_cast(h2v, f0.y);
        h2v c2 = __builtin_bit_cast(h2v, f0.z), c3 = __builtin_bit_cast(h2v, f0.w);
        h2v c4 = __builtin_bit_cast(h2v, f1.x), c5 = __builtin_bit_cast(h2v, f1.y);
        acc[0]+=w*(float)c0.x; acc[1]+=w*(float)c0.y; acc[2]+=w*(float)c1.x; acc[3]+=w*(float)c1.y;
        acc[4]+=w*(float)c2.x; acc[5]+=w*(float)c2.y; acc[6]+=w*(float)c3.x; acc[7]+=w*(float)c3.y;
        acc[8]+=w*(float)c4.x; acc[9]+=w*(float)c4.y; acc[10]+=w*(float)c5.x; acc[11]+=w*(float)c5.y;
    }
    float inv = 1.0f / (d + 1e-16f);
    float res[12];
    #pragma unroll
    for (int c = 0; c < 12; c++) {
        float v = acc[c] * inv;
        v += __shfl_xor(v, 1);
        v += __shfl_xor(v, 2);
        v += __shfl_xor(v, 4);
        res[c] = v * 0.125f;     // mean over 8 heads
    }
    if (h == 0) {
        float vals[12];
        float mx = -1e30f;
        #pragma unroll
        for (int c = 0; c < 12; c++) {
            float v = res[c] + gat_bias[c];
            v = (v - bn_mean[c]) * rsqrtf(bn_var[c] + 1e-5f) * bn_gamma[c] + bn_beta[c];
            vals[c] = v;
            mx = fmaxf(mx, v);
        }
        float sum = 0.f;
        #pragma unroll
        for (int c = 0; c < 12; c++) sum += __expf(vals[c] - mx);
        float lse = __logf(sum) + mx;
        #pragma unroll
        for (int c = 0; c < 12; c++) seq[(size_t)c * N_TOTAL_C + n] = vals[c] - lse;
    }
}

// ---------------- 4. X1 = seq(384x2048) @ w_ih1(128x2048)^T, split-K x16 ----------------
__global__ void gemm_x1(const float* __restrict__ A, const float* __restrict__ B,
                        float* __restrict__ C)
{
    __shared__ float As[32][33], Bs[32][33];
    const int K = 2048, N = 128;
    int tid = threadIdx.x;
    int tx = tid & 31, ty = tid >> 5;
    int bm = blockIdx.x * 32, bn = blockIdx.y * 32;
    int kbase = blockIdx.z * 128;
    float acc[4] = {0.f,0.f,0.f,0.f};
    for (int kk = 0; kk < 128; kk += 32) {
        int k0 = kbase + kk;
        #pragma unroll
        for (int i = 0; i < 4; i++) {
            int r = ty + i*8;
            As[r][tx] = A[(size_t)(bm + r) * K + k0 + tx];
            Bs[r][tx] = B[(size_t)(bn + r) * K + k0 + tx];
        }
        __syncthreads();
        #pragma unroll
        for (int k = 0; k < 32; k++) {
            float bv = Bs[tx][k];
            #pragma unroll
            for (int i = 0; i < 4; i++) acc[i] += As[ty + i*8][k] * bv;
        }
        __syncthreads();
    }
    #pragma unroll
    for (int i = 0; i < 4; i++)
        atomicAdd(&C[(size_t)(bm + ty + i*8) * N + bn + tx], acc[i]);
}

// ---------------- 5. fused LSTM1(2048->32) + LSTM2(32->128) ----------------
__global__ __launch_bounds__(512)
void lstm_fused(const float* __restrict__ X1, const float* __restrict__ w_hh1,
                const float* __restrict__ b_ih1, const float* __restrict__ b_hh1,
                const float* __restrict__ w_ih2, const float* __restrict__ w_hh2,
                const float* __restrict__ b_ih2, const float* __restrict__ b_hh2,
                float* __restrict__ H2)
{
    __shared__ float whh1[128*33];             // padded stride 33
    __shared__ float b1s[128];
    __shared__ float h1[32], c1[32];
    __shared__ __align__(16) _Float16 h1s[32]; // h1 as fp16 for dot2
    __shared__ __align__(16) _Float16 h2s[128];// h2 as fp16 for dot2
    __shared__ float c2[128];
    __shared__ float g1s[128], g2s[512];
    int tid = threadIdx.x;
    int b = blockIdx.x;

    // --- time-invariant weight preload into registers (fp16 pairs) ---
    h2v whh[64];
    {
        const float2* wh = (const float2*)(w_hh2 + (size_t)tid * 128);
        #pragma unroll
        for (int k = 0; k < 64; k++) {
            float2 v = wh[k];
            h2v t; t.x = (_Float16)v.x; t.y = (_Float16)v.y;
            whh[k] = t;
        }
    }
    h2v wih[16];
    {
        const float2* wi = (const float2*)(w_ih2 + (size_t)tid * 32);
        #pragma unroll
        for (int k = 0; k < 16; k++) {
            float2 v = wi[k];
            h2v t; t.x = (_Float16)v.x; t.y = (_Float16)v.y;
            wih[k] = t;
        }
    }
    float b2 = b_ih2[tid] + b_hh2[tid];

    for (int i = tid; i < 128*32; i += 512) whh1[(i >> 5)*33 + (i & 31)] = w_hh1[i];
    if (tid < 128) b1s[tid] = b_ih1[tid] + b_hh1[tid];
    if (tid < 32)  { h1[tid] = 0.f; c1[tid] = 0.f; h1s[tid] = (_Float16)0.f; }
    if (tid < 128) { c2[tid] = 0.f; h2s[tid] = (_Float16)0.f; }
    __syncthreads();

    for (int t = 0; t < 12; t++) {
        float p0 = b2, p1 = 0.f, p2 = 0.f, p3 = 0.f;
        #pragma unroll
        for (int j = 0; j < 16; j++) {
            float4 f = ((const float4*)h2s)[j];   // 8 halfs per ds_read_b128
            p0 = fdot2(__builtin_bit_cast(h2v, f.x), whh[j*4+0], p0);
            p1 = fdot2(__builtin_bit_cast(h2v, f.y), whh[j*4+1], p1);
            p2 = fdot2(__builtin_bit_cast(h2v, f.z), whh[j*4+2], p2);
            p3 = fdot2(__builtin_bit_cast(h2v, f.w), whh[j*4+3], p3);
        }
        float acc2 = (p0 + p1) + (p2 + p3);

        if (tid < 128) {
            const float* wr = &whh1[tid * 33];
            float acc = X1[((size_t)t*32 + b)*128 + tid] + b1s[tid];
            #pragma unroll
            for (int k = 0; k < 32; k++) acc += h1[k] * wr[k];
            g1s[tid] = acc;
        }
        __syncthreads();
        if (tid < 32) {
            float ig = sigf(g1s[tid]), fg = sigf(g1s[32+tid]);
            float gg = tanhf(g1s[64+tid]), og = sigf(g1s[96+tid]);
            float cn = fg * c1[tid] + ig * gg;
            c1[tid] = cn;
            float hn = og * tanhf(cn);
            h1[tid] = hn;
            h1s[tid] = (_Float16)hn;
        }
        __syncthreads();
        {
            float q0 = 0.f, q1 = 0.f, q2 = 0.f, q3 = 0.f;
            #pragma unroll
            for (int j = 0; j < 4; j++) {
                float4 f = ((const float4*)h1s)[j];
                q0 = fdot2(__builtin_bit_cast(h2v, f.x), wih[j*4+0], q0);
                q1 = fdot2(__builtin_bit_cast(h2v, f.y), wih[j*4+1], q1);
                q2 = fdot2(__builtin_bit_cast(h2v, f.z), wih[j*4+2], q2);
                q3 = fdot2(__builtin_bit_cast(h2v, f.w), wih[j*4+3], q3);
            }
            g2s[tid] = acc2 + (q0 + q1) + (q2 + q3);
        }
        __syncthreads();
        if (tid < 128) {
            float ig = sigf(g2s[tid]), fg = sigf(g2s[128+tid]);
            float gg = tanhf(g2s[256+tid]), og = sigf(g2s[384+tid]);
            float cn = fg * c2[tid] + ig * gg;
            c2[tid] = cn;
            float hn = og * tanhf(cn);
            h2s[tid] = (_Float16)hn;
            if (t >= 3) H2[((size_t)t*32 + b)*128 + tid] = hn;
        }
        __syncthreads();
    }
}

// ---------------- 6. out = H2[3:] (288x128) @ lin_w(2048x128)^T + lin_b ----------------
__global__ void gemm_out(const float* __restrict__ A, const float* __restrict__ B,
                         const float* __restrict__ bias, float* __restrict__ out)
{
    __shared__ float As[32][33], Bs[32][33];
    const int K = 128;
    int tid = threadIdx.x;
    int tx = tid & 31, ty = tid >> 5;
    int bm = blockIdx.x * 32, bn = blockIdx.y * 32;
    float acc[4] = {0.f,0.f,0.f,0.f};
    for (int k0 = 0; k0 < K; k0 += 32) {
        #pragma unroll
        for (int i = 0; i < 4; i++) {
            int r = ty + i*8;
            As[r][tx] = A[(size_t)(bm + r) * K + k0 + tx];
            Bs[r][tx] = B[(size_t)(bn + r) * K + k0 + tx];
        }
        __syncthreads();
        #pragma unroll
        for (int kk = 0; kk < 32; kk++) {
            float bv = Bs[tx][kk];
            #pragma unroll
            for (int i = 0; i < 4; i++) acc[i] += As[ty + i*8][kk] * bv;
        }
        __syncthreads();
    }
    int j = blockIdx.x;            // time slot within last 9 (rows are m = j*32 + b)
    int nn = bn + tx;
    float bv = bias[nn];
    #pragma unroll
    for (int i = 0; i < 4; i++) {
        int bb = ty + i*8;
        out[((size_t)bb * 2048 + nn) * 9 + j] = acc[i] + bv;
    }
}

extern "C" void kernel_launch(void* const* d_in, const int* in_sizes, int n_in,
                              void* d_out, int out_size, void* d_ws, size_t ws_size,
                              hipStream_t stream)
{
    const float* x        = (const float*)d_in[0];
    const int*   ei       = (const int*)  d_in[1];
    const float* W_gat    = (const float*)d_in[2];
    const float* a_src    = (const float*)d_in[3];
    const float* a_dst    = (const float*)d_in[4];
    const float* gat_bias = (const float*)d_in[5];
    const float* bn_gamma = (const float*)d_in[6];
    const float* bn_beta  = (const float*)d_in[7];
    const float* bn_mean  = (const float*)d_in[8];
    const float* bn_var   = (const float*)d_in[9];
    const float* w_ih1    = (const float*)d_in[10];
    const float* w_hh1    = (const float*)d_in[11];
    const float* b_ih1    = (const float*)d_in[12];
    const float* b_hh1    = (const float*)d_in[13];
    const float* w_ih2    = (const float*)d_in[14];
    const float* w_hh2    = (const float*)d_in[15];
    const float* b_ih2    = (const float*)d_in[16];
    const float* b_hh2    = (const float*)d_in[17];
    const float* lin_w    = (const float*)d_in[18];
    const float* lin_b    = (const float*)d_in[19];
    float* out = (float*)d_out;

    float* ws = (float*)d_ws;
    _Float16* xpp = (_Float16*)ws;          // 65536*128 halfs = 4194304 float slots (16 MB)
    float* seq  = ws   + 4194304;           // 12*65536 = 786432
    float* X1   = seq  + 786432;            // 384*128  = 49152
    float* H2   = X1   + 49152;             // 384*128  = 49152
    int* rowptr = (int*)(H2 + 49152);       // 65537 (reserve 65540 for 16B align)
    int* cursor = rowptr + 65540;           // 65536
    int* deg    = cursor + 65536;           // 65536
    int* csr    = deg    + 65536;           // 1048576
    // total ~24.6 MB of d_ws

    hipMemsetAsync(deg, 0, 65536 * sizeof(int), stream);
    hipMemsetAsync(X1, 0, 49152 * sizeof(float), stream);
    prep_kernel <<<3072, 256, 0, stream>>>(x, W_gat, a_src, a_dst, xpp, ei, deg);
    scan_build  <<<1, 1024, 0, stream>>>(deg, rowptr, cursor);
    edge_scatter<<<512, 256, 0, stream>>>(ei, cursor, csr);
    gat_aggregate<<<2048, 256, 0, stream>>>(xpp, rowptr, csr,
                                            gat_bias, bn_gamma, bn_beta, bn_mean, bn_var, seq);
    gemm_x1<<<dim3(12, 4, 16), 256, 0, stream>>>(seq, w_ih1, X1);
    lstm_fused<<<32, 512, 0, stream>>>(X1, w_hh1, b_ih1, b_hh1, w_ih2, w_hh2, b_ih2, b_hh2, H2);
    gemm_out<<<dim3(9, 64), 256, 0, stream>>>(H2 + 96*128, lin_w, lin_b, out);
}

// Round 8
// 312.847 us; speedup vs baseline: 1.7357x; 1.0421x over previous
//
#include <hip/hip_runtime.h>
#include <math.h>

#define N_EDGES_C 1048576
#define N_TOTAL_C 65536

typedef _Float16 h2v __attribute__((ext_vector_type(2)));
typedef _Float16 h4v __attribute__((ext_vector_type(4)));
typedef int i4v __attribute__((ext_vector_type(4)));   // native vec4: valid for nontemporal builtins

#if defined(__has_builtin)
#if __has_builtin(__builtin_amdgcn_fdot2)
#define HAS_FDOT2 1
#endif
#endif

__device__ __forceinline__ float fdot2(h2v a, h2v b, float c) {
#ifdef HAS_FDOT2
    return __builtin_amdgcn_fdot2(a, b, c, false);
#else
    return c + (float)a.x * (float)b.x + (float)a.y * (float)b.y;
#endif
}

__device__ __forceinline__ float sigf(float x){ return 1.0f/(1.0f+expf(-x)); }
__device__ __forceinline__ float lrelu(float x){ return (x>=0.f)? x : 0.2f*x; }

// xpp row layout: 128 halfs (256 B) per node = 8 head slots x 16 halfs:
//   [ch0..ch11 fp16 | asrc_h fp32 (halfs 12-13) | adst_h fp32 (halfs 14-15)]

// ---------------- 1. fused prep: node transform (blocks 0..2047, 8 thr/node)
//                   + degree count & edge rank (blocks 2048..3071) ----------------
// rank[e] = this edge's arrival index among same-dst edges (atomicAdd return) ->
// scatter position rowptr[dst]+rank[e] is unique WITHOUT scatter-time atomics
// (round-7: cursor far-atomics ~32B each accounted for ~32MB of WRITE_SIZE).
__global__ void prep_kernel(const float* __restrict__ x, const float* __restrict__ Wg,
                            const float* __restrict__ a_src, const float* __restrict__ a_dst,
                            _Float16* __restrict__ xpp,
                            const int* __restrict__ ei, int* __restrict__ deg,
                            int* __restrict__ rank)
{
    int tid = threadIdx.x;
    if (blockIdx.x >= 2048) {        // --- degree count + rank: 4 edges/thread ---
        int i = (blockIdx.x - 2048) * 256 + tid;
        i4v d = __builtin_nontemporal_load((const i4v*)(ei + N_EDGES_C) + i);
        i4v r;
        r.x = atomicAdd(&deg[d.x], 1);
        r.y = atomicAdd(&deg[d.y], 1);
        r.z = atomicAdd(&deg[d.z], 1);
        r.w = atomicAdd(&deg[d.w], 1);
        __builtin_nontemporal_store(r, (i4v*)rank + i);
        return;
    }
    __shared__ float Ws[12*96];
    __shared__ float as_s[96], ad_s[96];
    for (int i = tid; i < 1152; i += 256) Ws[i] = Wg[i];
    if (tid < 96) { as_s[tid] = a_src[tid]; ad_s[tid] = a_dst[tid]; }
    __syncthreads();
    int gid = blockIdx.x * 256 + tid;
    int n = gid >> 3;
    int h = gid & 7;
    const float4* xv = (const float4*)(x + (size_t)n * 12);   // 8 lanes share -> L1 broadcast
    float4 v0 = xv[0], v1 = xv[1], v2 = xv[2];
    float xr[12] = {v0.x,v0.y,v0.z,v0.w, v1.x,v1.y,v1.z,v1.w, v2.x,v2.y,v2.z,v2.w};
    float xp_[12];
    #pragma unroll
    for (int c = 0; c < 12; c++) {
        float acc = 0.f;
        #pragma unroll
        for (int k = 0; k < 12; k++) acc += xr[k] * Ws[k*96 + h*12 + c];
        xp_[c] = acc;
    }
    float sa = 0.f, sd = 0.f;
    #pragma unroll
    for (int c = 0; c < 12; c++) { sa += xp_[c]*as_s[h*12+c]; sd += xp_[c]*ad_s[h*12+c]; }
    union { _Float16 hh[16]; float ff[8]; float4 f4[2]; } s;
    #pragma unroll
    for (int c = 0; c < 12; c++) s.hh[c] = (_Float16)xp_[c];
    s.ff[6] = sa;            // halfs 12-13
    s.ff[7] = sd;            // halfs 14-15
    float4* o = (float4*)(xpp + (size_t)gid * 16);   // byte addr gid*32: coalesced
    o[0] = s.f4[0];
    o[1] = s.f4[1];
}

// ---------------- 2b. exclusive scan over 65536 degrees (single block, int4 I/O) ----------------
__global__ void scan_build(const int* __restrict__ deg, int* __restrict__ rowptr)
{
    __shared__ int sums[1024];
    int tid = threadIdx.x;
    int4 v[16];
    const int4* deg4 = (const int4*)deg;
    #pragma unroll
    for (int j = 0; j < 16; j++) v[j] = deg4[tid*16 + j];
    int s = 0;
    #pragma unroll
    for (int j = 0; j < 16; j++) s += v[j].x + v[j].y + v[j].z + v[j].w;
    sums[tid] = s;
    __syncthreads();
    for (int off = 1; off < 1024; off <<= 1) {
        int t = 0;
        if (tid >= off) t = sums[tid - off];
        __syncthreads();
        if (tid >= off) sums[tid] += t;
        __syncthreads();
    }
    int run = sums[tid] - s;   // exclusive prefix of this chunk
    int4* rp4 = (int4*)rowptr;
    #pragma unroll
    for (int j = 0; j < 16; j++) {
        int4 r;
        r.x = run; run += v[j].x;
        r.y = run; run += v[j].y;
        r.z = run; run += v[j].z;
        r.w = run; run += v[j].w;
        rp4[tid*16 + j] = r;
    }
    if (tid == 1023) rowptr[65536] = run;
}

// ---------------- 2c. dst-range-binned, ATOMIC-FREE CSR scatter ----------------
// Position = rowptr[dst] + rank[e]: unique by construction. Group g (blockIdx&7,
// XCD round-robin heuristic) handles dst range [g*8192,(g+1)*8192) -> its csr
// writes land in one contiguous 512KB slice, full-line writebacks from one L2.
__global__ void edge_scatter(const int* __restrict__ ei, const int* __restrict__ rank,
                             const int* __restrict__ rowptr, int* __restrict__ csr)
{
    int g = blockIdx.x & 7;
    int slice = blockIdx.x >> 3;          // 0..63
    const i4v* dst4 = (const i4v*)(ei + N_EDGES_C);
    const i4v* src4 = (const i4v*)ei;
    const i4v* rnk4 = (const i4v*)rank;
    for (int i = threadIdx.x; i < 4096; i += 256) {
        int idx = slice * 4096 + i;
        i4v d = __builtin_nontemporal_load(&dst4[idx]);
        i4v s = __builtin_nontemporal_load(&src4[idx]);
        i4v r = __builtin_nontemporal_load(&rnk4[idx]);
        if ((d.x >> 13) == g) csr[rowptr[d.x] + r.x] = s.x;
        if ((d.y >> 13) == g) csr[rowptr[d.y] + r.y] = s.y;
        if ((d.z >> 13) == g) csr[rowptr[d.z] + r.z] = s.z;
        if ((d.w >> 13) == g) csr[rowptr[d.w] + r.w] = s.w;
    }
}

// ---------------- 3. per-(node,head) softmax aggregation + BN + log_softmax ----------------
__global__ void gat_aggregate(const _Float16* __restrict__ xpp,
                              const int* __restrict__ rowptr, const int* __restrict__ csr_src,
                              const float* __restrict__ gat_bias, const float* __restrict__ bn_gamma,
                              const float* __restrict__ bn_beta, const float* __restrict__ bn_mean,
                              const float* __restrict__ bn_var, float* __restrict__ seq)
{
    int gid = blockIdx.x * 256 + threadIdx.x;
    int n = gid >> 3;
    int h = gid & 7;

    float acc[12];
    float adst_n, d;
    {
        const float4* p = (const float4*)(xpp + (size_t)n*128 + h*16);
        float4 f0 = p[0], f1 = p[1];
        float asrc_n = f1.z;
        adst_n = f1.w;
        float w = __expf(lrelu(asrc_n + adst_n));   // self-loop term
        d = w;
        h2v c0 = __builtin_bit_cast(h2v, f0.x), c1 = __builtin_bit_cast(h2v, f0.y);
        h2v c2 = __builtin_bit_cast(h2v, f0.z), c3 = __builtin_bit_cast(h2v, f0.w);
        h2v c4 = __builtin_bit_cast(h2v, f1.x), c5 = __builtin_bit_cast(h2v, f1.y);
        acc[0]=w*(float)c0.x; acc[1]=w*(float)c0.y; acc[2]=w*(float)c1.x; acc[3]=w*(float)c1.y;
        acc[4]=w*(float)c2.x; acc[5]=w*(float)c2.y; acc[6]=w*(float)c3.x; acc[7]=w*(float)c3.y;
        acc[8]=w*(float)c4.x; acc[9]=w*(float)c4.y; acc[10]=w*(float)c5.x; acc[11]=w*(float)c5.y;
    }
    int beg = rowptr[n], end = rowptr[n+1];
    for (int i = beg; i < end; i++) {
        int src = csr_src[i];
        const float4* p = (const float4*)(xpp + (size_t)src*128 + h*16);
        float4 f0 = p[0], f1 = p[1];
        float w = __expf(lrelu(f1.z + adst_n));
        d += w;
        h2v c0 = __builtin_bit_cast(h2v, f0.x), c1 = __builtin_bit_cast(h2v, f0.y);
        h2v c2 = __builtin_bit_cast(h2v, f0.z), c3 = __builtin_bit_cast(h2v, f0.w);
        h2v c4 = __builtin_bit_cast(h2v, f1.x), c5 = __builtin_bit_cast(h2v, f1.y);
        acc[0]+=w*(float)c0.x; acc[1]+=w*(float)c0.y; acc[2]+=w*(float)c1.x; acc[3]+=w*(float)c1.y;
        acc[4]+=w*(float)c2.x; acc[5]+=w*(float)c2.y; acc[6]+=w*(float)c3.x; acc[7]+=w*(float)c3.y;
        acc[8]+=w*(float)c4.x; acc[9]+=w*(float)c4.y; acc[10]+=w*(float)c5.x; acc[11]+=w*(float)c5.y;
    }
    float inv = 1.0f / (d + 1e-16f);
    float res[12];
    #pragma unroll
    for (int c = 0; c < 12; c++) {
        float v = acc[c] * inv;
        v += __shfl_xor(v, 1);
        v += __shfl_xor(v, 2);
        v += __shfl_xor(v, 4);
        res[c] = v * 0.125f;     // mean over 8 heads
    }
    if (h == 0) {
        float vals[12];
        float mx = -1e30f;
        #pragma unroll
        for (int c = 0; c < 12; c++) {
            float v = res[c] + gat_bias[c];
            v = (v - bn_mean[c]) * rsqrtf(bn_var[c] + 1e-5f) * bn_gamma[c] + bn_beta[c];
            vals[c] = v;
            mx = fmaxf(mx, v);
        }
        float sum = 0.f;
        #pragma unroll
        for (int c = 0; c < 12; c++) sum += __expf(vals[c] - mx);
        float lse = __logf(sum) + mx;
        #pragma unroll
        for (int c = 0; c < 12; c++) seq[(size_t)c * N_TOTAL_C + n] = vals[c] - lse;
    }
}

// ---------------- 4. X1 = seq(384x2048) @ w_ih1(128x2048)^T, split-K x16 ----------------
__global__ void gemm_x1(const float* __restrict__ A, const float* __restrict__ B,
                        float* __restrict__ C)
{
    __shared__ float As[32][33], Bs[32][33];
    const int K = 2048, N = 128;
    int tid = threadIdx.x;
    int tx = tid & 31, ty = tid >> 5;
    int bm = blockIdx.x * 32, bn = blockIdx.y * 32;
    int kbase = blockIdx.z * 128;
    float acc[4] = {0.f,0.f,0.f,0.f};
    for (int kk = 0; kk < 128; kk += 32) {
        int k0 = kbase + kk;
        #pragma unroll
        for (int i = 0; i < 4; i++) {
            int r = ty + i*8;
            As[r][tx] = A[(size_t)(bm + r) * K + k0 + tx];
            Bs[r][tx] = B[(size_t)(bn + r) * K + k0 + tx];
        }
        __syncthreads();
        #pragma unroll
        for (int k = 0; k < 32; k++) {
            float bv = Bs[tx][k];
            #pragma unroll
            for (int i = 0; i < 4; i++) acc[i] += As[ty + i*8][k] * bv;
        }
        __syncthreads();
    }
    #pragma unroll
    for (int i = 0; i < 4; i++)
        atomicAdd(&C[(size_t)(bm + ty + i*8) * N + bn + tx], acc[i]);
}

// ---------------- 5. fused LSTM1(2048->32) + LSTM2(32->128) ----------------
__global__ __launch_bounds__(512)
void lstm_fused(const float* __restrict__ X1, const float* __restrict__ w_hh1,
                const float* __restrict__ b_ih1, const float* __restrict__ b_hh1,
                const float* __restrict__ w_ih2, const float* __restrict__ w_hh2,
                const float* __restrict__ b_ih2, const float* __restrict__ b_hh2,
                float* __restrict__ H2)
{
    __shared__ float whh1[128*33];             // padded stride 33
    __shared__ float b1s[128];
    __shared__ float h1[32], c1[32];
    __shared__ __align__(16) _Float16 h1s[32]; // h1 as fp16 for dot2
    __shared__ __align__(16) _Float16 h2s[128];// h2 as fp16 for dot2
    __shared__ float c2[128];
    __shared__ float g1s[128], g2s[512];
    int tid = threadIdx.x;
    int b = blockIdx.x;

    // --- time-invariant weight preload into registers (fp16 pairs) ---
    h2v whh[64];
    {
        const float2* wh = (const float2*)(w_hh2 + (size_t)tid * 128);
        #pragma unroll
        for (int k = 0; k < 64; k++) {
            float2 v = wh[k];
            h2v t; t.x = (_Float16)v.x; t.y = (_Float16)v.y;
            whh[k] = t;
        }
    }
    h2v wih[16];
    {
        const float2* wi = (const float2*)(w_ih2 + (size_t)tid * 32);
        #pragma unroll
        for (int k = 0; k < 16; k++) {
            float2 v = wi[k];
            h2v t; t.x = (_Float16)v.x; t.y = (_Float16)v.y;
            wih[k] = t;
        }
    }
    float b2 = b_ih2[tid] + b_hh2[tid];

    for (int i = tid; i < 128*32; i += 512) whh1[(i >> 5)*33 + (i & 31)] = w_hh1[i];
    if (tid < 128) b1s[tid] = b_ih1[tid] + b_hh1[tid];
    if (tid < 32)  { h1[tid] = 0.f; c1[tid] = 0.f; h1s[tid] = (_Float16)0.f; }
    if (tid < 128) { c2[tid] = 0.f; h2s[tid] = (_Float16)0.f; }
    __syncthreads();

    for (int t = 0; t < 12; t++) {
        float p0 = b2, p1 = 0.f, p2 = 0.f, p3 = 0.f;
        #pragma unroll
        for (int j = 0; j < 16; j++) {
            float4 f = ((const float4*)h2s)[j];   // 8 halfs per ds_read_b128
            p0 = fdot2(__builtin_bit_cast(h2v, f.x), whh[j*4+0], p0);
            p1 = fdot2(__builtin_bit_cast(h2v, f.y), whh[j*4+1], p1);
            p2 = fdot2(__builtin_bit_cast(h2v, f.z), whh[j*4+2], p2);
            p3 = fdot2(__builtin_bit_cast(h2v, f.w), whh[j*4+3], p3);
        }
        float acc2 = (p0 + p1) + (p2 + p3);

        if (tid < 128) {
            const float* wr = &whh1[tid * 33];
            float acc = X1[((size_t)t*32 + b)*128 + tid] + b1s[tid];
            #pragma unroll
            for (int k = 0; k < 32; k++) acc += h1[k] * wr[k];
            g1s[tid] = acc;
        }
        __syncthreads();
        if (tid < 32) {
            float ig = sigf(g1s[tid]), fg = sigf(g1s[32+tid]);
            float gg = tanhf(g1s[64+tid]), og = sigf(g1s[96+tid]);
            float cn = fg * c1[tid] + ig * gg;
            c1[tid] = cn;
            float hn = og * tanhf(cn);
            h1[tid] = hn;
            h1s[tid] = (_Float16)hn;
        }
        __syncthreads();
        {
            float q0 = 0.f, q1 = 0.f, q2 = 0.f, q3 = 0.f;
            #pragma unroll
            for (int j = 0; j < 4; j++) {
                float4 f = ((const float4*)h1s)[j];
                q0 = fdot2(__builtin_bit_cast(h2v, f.x), wih[j*4+0], q0);
                q1 = fdot2(__builtin_bit_cast(h2v, f.y), wih[j*4+1], q1);
                q2 = fdot2(__builtin_bit_cast(h2v, f.z), wih[j*4+2], q2);
                q3 = fdot2(__builtin_bit_cast(h2v, f.w), wih[j*4+3], q3);
            }
            g2s[tid] = acc2 + (q0 + q1) + (q2 + q3);
        }
        __syncthreads();
        if (tid < 128) {
            float ig = sigf(g2s[tid]), fg = sigf(g2s[128+tid]);
            float gg = tanhf(g2s[256+tid]), og = sigf(g2s[384+tid]);
            float cn = fg * c2[tid] + ig * gg;
            c2[tid] = cn;
            float hn = og * tanhf(cn);
            h2s[tid] = (_Float16)hn;
            if (t >= 3) H2[((size_t)t*32 + b)*128 + tid] = hn;
        }
        __syncthreads();
    }
}

// ---------------- 6. out = H2[3:] (288x128) @ lin_w(2048x128)^T + lin_b ----------------
__global__ void gemm_out(const float* __restrict__ A, const float* __restrict__ B,
                         const float* __restrict__ bias, float* __restrict__ out)
{
    __shared__ float As[32][33], Bs[32][33];
    const int K = 128;
    int tid = threadIdx.x;
    int tx = tid & 31, ty = tid >> 5;
    int bm = blockIdx.x * 32, bn = blockIdx.y * 32;
    float acc[4] = {0.f,0.f,0.f,0.f};
    for (int k0 = 0; k0 < K; k0 += 32) {
        #pragma unroll
        for (int i = 0; i < 4; i++) {
            int r = ty + i*8;
            As[r][tx] = A[(size_t)(bm + r) * K + k0 + tx];
            Bs[r][tx] = B[(size_t)(bn + r) * K + k0 + tx];
        }
        __syncthreads();
        #pragma unroll
        for (int kk = 0; kk < 32; kk++) {
            float bv = Bs[tx][kk];
            #pragma unroll
            for (int i = 0; i < 4; i++) acc[i] += As[ty + i*8][kk] * bv;
        }
        __syncthreads();
    }
    int j = blockIdx.x;            // time slot within last 9 (rows are m = j*32 + b)
    int nn = bn + tx;
    float bv = bias[nn];
    #pragma unroll
    for (int i = 0; i < 4; i++) {
        int bb = ty + i*8;
        out[((size_t)bb * 2048 + nn) * 9 + j] = acc[i] + bv;
    }
}

extern "C" void kernel_launch(void* const* d_in, const int* in_sizes, int n_in,
                              void* d_out, int out_size, void* d_ws, size_t ws_size,
                              hipStream_t stream)
{
    const float* x        = (const float*)d_in[0];
    const int*   ei       = (const int*)  d_in[1];
    const float* W_gat    = (const float*)d_in[2];
    const float* a_src    = (const float*)d_in[3];
    const float* a_dst    = (const float*)d_in[4];
    const float* gat_bias = (const float*)d_in[5];
    const float* bn_gamma = (const float*)d_in[6];
    const float* bn_beta  = (const float*)d_in[7];
    const float* bn_mean  = (const float*)d_in[8];
    const float* bn_var   = (const float*)d_in[9];
    const float* w_ih1    = (const float*)d_in[10];
    const float* w_hh1    = (const float*)d_in[11];
    const float* b_ih1    = (const float*)d_in[12];
    const float* b_hh1    = (const float*)d_in[13];
    const float* w_ih2    = (const float*)d_in[14];
    const float* w_hh2    = (const float*)d_in[15];
    const float* b_ih2    = (const float*)d_in[16];
    const float* b_hh2    = (const float*)d_in[17];
    const float* lin_w    = (const float*)d_in[18];
    const float* lin_b    = (const float*)d_in[19];
    float* out = (float*)d_out;

    float* ws = (float*)d_ws;
    _Float16* xpp = (_Float16*)ws;          // 65536*128 halfs = 4194304 float slots (16 MB)
    float* seq  = ws   + 4194304;           // 12*65536 = 786432
    float* X1   = seq  + 786432;            // 384*128  = 49152
    float* H2   = X1   + 49152;             // 384*128  = 49152
    int* rowptr = (int*)(H2 + 49152);       // 65537 (reserve 65540 for 16B align)
    int* deg    = rowptr + 65540;           // 65536
    int* rank   = deg    + 65536;           // 1048576
    int* csr    = rank   + 1048576;         // 1048576
    // total ~28.3 MB of d_ws

    hipMemsetAsync(deg, 0, 65536 * sizeof(int), stream);
    hipMemsetAsync(X1, 0, 49152 * sizeof(float), stream);
    prep_kernel <<<3072, 256, 0, stream>>>(x, W_gat, a_src, a_dst, xpp, ei, deg, rank);
    scan_build  <<<1, 1024, 0, stream>>>(deg, rowptr);
    edge_scatter<<<512, 256, 0, stream>>>(ei, rank, rowptr, csr);
    gat_aggregate<<<2048, 256, 0, stream>>>(xpp, rowptr, csr,
                                            gat_bias, bn_gamma, bn_beta, bn_mean, bn_var, seq);
    gemm_x1<<<dim3(12, 4, 16), 256, 0, stream>>>(seq, w_ih1, X1);
    lstm_fused<<<32, 512, 0, stream>>>(X1, w_hh1, b_ih1, b_hh1, w_ih2, w_hh2, b_ih2, b_hh2, H2);
    gemm_out<<<dim3(9, 64), 256, 0, stream>>>(H2 + 96*128, lin_w, lin_b, out);
}